// Round 1
// 211.739 us; speedup vs baseline: 1.0438x; 1.0438x over previous
//
#include <hip/hip_runtime.h>
#include <hip/hip_bf16.h>

// Problem constants (AttentionConv2d): B=32, CIN=256, H=W=32 -> N=1024,
// DK=DV=128, HEADS=8 -> per-head d=16, OUT=256.
#define BATCH 32
#define CIN   256
#define NPOS  1024
#define DKC   128
#define DVC   128
#define HEADS 8
#define OUTC  256

typedef __bf16 bf16x8 __attribute__((ext_vector_type(8)));
typedef __bf16 bf16x4 __attribute__((ext_vector_type(4)));
typedef float  f32x4  __attribute__((ext_vector_type(4)));
typedef float  f32x16 __attribute__((ext_vector_type(16)));

// q pre-scale: dk^-0.5 * log2(e), so attention can use raw exp2.
#define QSCALE 0.3606737602f

__device__ inline bf16x8 load8(const __bf16* p) {
    return *reinterpret_cast<const bf16x8*>(p);
}
__device__ inline f32x4 fzero4() {
    f32x4 z;
#pragma unroll
    for (int i = 0; i < 4; ++i) z[i] = 0.0f;
    return z;
}
__device__ inline float fexp2(float x) {
#if __has_builtin(__builtin_amdgcn_exp2f)
    return __builtin_amdgcn_exp2f(x);
#else
    return exp2f(x);
#endif
}

// ---------------------------------------------------------------------------
// Kernel D: dtype detector (fp32-as-bf16 halfwords have huge exponents).
// ---------------------------------------------------------------------------
__global__ __launch_bounds__(256) void detect_dtype(const unsigned short* __restrict__ xraw,
                                                    int* __restrict__ flag) {
    __shared__ int s;
    if (threadIdx.x == 0) s = 0;
    __syncthreads();
    int cnt = 0;
#pragma unroll
    for (int j = 0; j < 64; ++j) {
        unsigned short u = xraw[threadIdx.x * 64 + j];
        unsigned int e = (u >> 7) & 0xFF;
        if (e >= 0x92) cnt++;
    }
    if (cnt) atomicAdd(&s, cnt);
    __syncthreads();
    if (threadIdx.x == 0) *flag = (s > 0) ? 1 : 0;
}

// ---------------------------------------------------------------------------
// Kernel C: convert all weight/bias tensors to canonical bf16 in one launch.
// Weights land in ONE contiguous wcat[512][256] (qkv rows 0..383, conv rows
// 384..511) and bcat[512] so the GEMM inner loop has no pointer selects.
// ---------------------------------------------------------------------------
#define CV_WQKV 98304                    // w_qkv 384*256 -> wcat[0..)
#define CV_WOUT (CV_WQKV + 32768)        // w_out 128*256 -> wcat[98304..)
#define CV_BQKV (CV_WOUT + 384)          // b_qkv -> bcat[0..384)
#define CV_BOUT (CV_BQKV + 128)          // b_out -> bcat[384..512)
#define CV_WATT (CV_BOUT + 16384)        // w_attn 128*128
#define CV_BATT (CV_WATT + 128)          // b_attn
__global__ __launch_bounds__(256) void convert_all(
    const void* __restrict__ w_qkv, const void* __restrict__ b_qkv,
    const void* __restrict__ w_attn, const void* __restrict__ b_attn,
    const void* __restrict__ w_out, const void* __restrict__ b_out,
    __bf16* __restrict__ wcat, __bf16* __restrict__ bcat,
    __bf16* __restrict__ w_attnc, __bf16* __restrict__ b_attnc,
    const int* __restrict__ flag) {
    int i = blockIdx.x * 256 + threadIdx.x;
    const void* src; __bf16* dst; int j;
    if      (i < CV_WQKV) { src = w_qkv;  j = i;           dst = wcat + i; }
    else if (i < CV_WOUT) { src = w_out;  j = i - CV_WQKV; dst = wcat + i; }
    else if (i < CV_BQKV) { src = b_qkv;  j = i - CV_WOUT; dst = bcat + j; }
    else if (i < CV_BOUT) { src = b_out;  j = i - CV_BQKV; dst = bcat + 384 + j; }
    else if (i < CV_WATT) { src = w_attn; j = i - CV_BOUT; dst = w_attnc + j; }
    else if (i < CV_BATT) { src = b_attn; j = i - CV_WATT; dst = b_attnc + j; }
    else return;
    if (*flag) *dst = (__bf16)((const float*)src)[j];
    else       *dst = ((const __bf16*)src)[j];
}

// ---------------------------------------------------------------------------
// Kernel X: transpose+convert x [B][C][N] (fp32 or bf16) -> xT [B][N][C] bf16.
// 64x64 tiles; reads fully coalesced (256B/wave), writes 128B-contiguous rows.
// grid (N/64=16, C/64=4, B=32) = 2048 blocks, block 256.
// ---------------------------------------------------------------------------
__global__ __launch_bounds__(256) void xpose(
    const void* __restrict__ xv, __bf16* __restrict__ xT,
    const int* __restrict__ flag) {
    __shared__ __bf16 tile[64][72];  // [n][c], pad to 72 (9216 B)
    bool isf32 = (*flag != 0);
    int b = blockIdx.z, c0 = blockIdx.y * 64, n0 = blockIdx.x * 64;
    int t = threadIdx.x, nl = t & 63, cb = t >> 6;
#pragma unroll
    for (int cs = 0; cs < 16; ++cs) {
        int cw = cs * 4 + cb;
        size_t gi = ((size_t)b * CIN + c0 + cw) * NPOS + n0 + nl;
        float v = isf32 ? ((const float*)xv)[gi] : (float)((const __bf16*)xv)[gi];
        tile[nl][cw] = (__bf16)v;
    }
    __syncthreads();
    int row = t >> 2, seg = t & 3;
    bf16x8 v0 = *reinterpret_cast<const bf16x8*>(&tile[row][seg * 16]);
    bf16x8 v1 = *reinterpret_cast<const bf16x8*>(&tile[row][seg * 16 + 8]);
    __bf16* dst = xT + ((size_t)b * NPOS + n0 + row) * CIN + c0 + seg * 16;
    *reinterpret_cast<bf16x8*>(dst)     = v0;
    *reinterpret_cast<bf16x8*>(dst + 8) = v1;
}

// ---------------------------------------------------------------------------
// Kernel 1 (v2): LDS-free, barrier-free register-streaming QKV+conv GEMM.
// C[o=512][n=B*1024] = wcat[512][256] x xT^T; both operands are direct 16B
// load8 in native mfma_16x16x32 fragment layout (row-major [*][256] bf16).
// Wave tile = 64 rows x 64 cols (acc 4x4 f32x4 = 64 VGPR). Block = 4 waves =
// 256 rows. grid (N/64=16, B=32, rowhalf=2) = 1024 blocks -> 4 blocks/CU,
// 16 waves/CU. Epilogue: q/k as coalesced bf16x4 stores; v/conv scalar.
// ---------------------------------------------------------------------------
__global__ __launch_bounds__(256, 4) void qkv_conv_gemm2(
    const __bf16* __restrict__ xT,    // [B][N][256]
    const __bf16* __restrict__ wcat,  // [512][256]
    const __bf16* __restrict__ bcat,  // [512]
    __bf16* __restrict__ q_ws,        // [B*H][N][16]
    __bf16* __restrict__ k_ws,        // [B*H][N][16]
    __bf16* __restrict__ v_ws,        // [B*H][16][N]
    void* __restrict__ out,           // [B][256][N], dtype per flag
    const int* __restrict__ flag)
{
    int b   = blockIdx.y;
    int n0  = blockIdx.x * 64;
    int z   = blockIdx.z;
    int wave = threadIdx.x >> 6;
    int lane = threadIdx.x & 63;
    int quad = lane >> 4, colid = lane & 15;
    int row0 = z * 256 + wave * 64;

    const __bf16* xp = xT + ((size_t)b * NPOS + n0) * CIN;
    const __bf16* wp = wcat + (size_t)(row0 + colid) * CIN + quad * 8;
    const __bf16* bp = xp + (size_t)colid * CIN + quad * 8;

    f32x4 acc[4][4];
#pragma unroll
    for (int rt = 0; rt < 4; ++rt)
#pragma unroll
        for (int st = 0; st < 4; ++st) acc[rt][st] = fzero4();

#pragma unroll
    for (int k0 = 0; k0 < CIN; k0 += 32) {
        bf16x8 aA[4], bB[4];
#pragma unroll
        for (int rt = 0; rt < 4; ++rt)
            aA[rt] = load8(wp + (size_t)rt * 16 * CIN + k0);
#pragma unroll
        for (int st = 0; st < 4; ++st)
            bB[st] = load8(bp + (size_t)st * 16 * CIN + k0);
#pragma unroll
        for (int rt = 0; rt < 4; ++rt)
#pragma unroll
            for (int st = 0; st < 4; ++st)
                acc[rt][st] = __builtin_amdgcn_mfma_f32_16x16x32_bf16(aA[rt], bB[st], acc[rt][st], 0, 0, 0);
    }

    bool isf32 = (*flag != 0);
#pragma unroll
    for (int rt = 0; rt < 4; ++rt) {
        int obase = row0 + rt * 16;  // uniform per wave; 16 consecutive o
        float bias[4];
#pragma unroll
        for (int r = 0; r < 4; ++r) bias[r] = (float)bcat[obase + quad * 4 + r];

        if (obase < DKC) {                       // ---- q: [B*H][N][16]
            int h = obase >> 4;
            __bf16* qb = q_ws + (((size_t)b * HEADS + h) * NPOS + n0) * 16 + quad * 4;
#pragma unroll
            for (int st = 0; st < 4; ++st) {
                bf16x4 ov;
#pragma unroll
                for (int r = 0; r < 4; ++r)
                    ov[r] = (__bf16)((acc[rt][st][r] + bias[r]) * QSCALE);
                *reinterpret_cast<bf16x4*>(qb + (size_t)(st * 16 + colid) * 16) = ov;
            }
        } else if (obase < 2 * DKC) {            // ---- k: [B*H][N][16]
            int h = (obase - DKC) >> 4;
            __bf16* kb = k_ws + (((size_t)b * HEADS + h) * NPOS + n0) * 16 + quad * 4;
#pragma unroll
            for (int st = 0; st < 4; ++st) {
                bf16x4 ov;
#pragma unroll
                for (int r = 0; r < 4; ++r)
                    ov[r] = (__bf16)(acc[rt][st][r] + bias[r]);
                *reinterpret_cast<bf16x4*>(kb + (size_t)(st * 16 + colid) * 16) = ov;
            }
        } else if (obase < 384) {                // ---- v: [B*H][16][N]
            int h = (obase - 2 * DKC) >> 4;
            __bf16* vb = v_ws + (((size_t)b * HEADS + h) * 16 + quad * 4) * NPOS + n0 + colid;
#pragma unroll
            for (int r = 0; r < 4; ++r)
#pragma unroll
                for (int st = 0; st < 4; ++st)
                    vb[(size_t)r * NPOS + st * 16] = (__bf16)(acc[rt][st][r] + bias[r]);
        } else {                                  // ---- conv out: [B][0..128][N]
            int oc = obase - 384 + quad * 4;
#pragma unroll
            for (int r = 0; r < 4; ++r) {
                size_t ob = ((size_t)b * OUTC + oc + r) * NPOS + n0 + colid;
#pragma unroll
                for (int st = 0; st < 4; ++st) {
                    float v = acc[rt][st][r] + bias[r];
                    if (isf32) ((float*)out)[ob + st * 16] = v;
                    else       ((__bf16*)out)[ob + st * 16] = (__bf16)v;
                }
            }
        }
    }
}

// ---------------------------------------------------------------------------
// Kernel 2: attention on NATIVE MFMA shapes only (unchanged).
// grid (N/128=8, B*H=256), block 256 (4 independent waves).
// ---------------------------------------------------------------------------
#define PSTR 80  // bytes per query row in the P strip (16B-aligned, odd*16)
__global__ __launch_bounds__(256) void attention_kernel(
    const __bf16* __restrict__ q_ws,   // [B*H][N][16]
    const __bf16* __restrict__ k_ws,   // [B*H][N][16]
    const __bf16* __restrict__ v_ws,   // [B*H][16][N]
    __bf16* __restrict__ attn_ws)      // [B][N][128]
{
    __shared__ __align__(16) char p_lds[4][2][32 * PSTR];  // 20.5 KB
    int bh   = blockIdx.y;
    int b    = bh >> 3, h = bh & 7;
    int wave = threadIdx.x >> 6;
    int lane = threadIdx.x & 63;
    int l5   = lane & 31, hi = lane >> 5;       // 32x32 frag coords
    int quad = lane >> 4, colid = lane & 15;    // 16x16 frag coords
    int nq0  = (blockIdx.x * 4 + wave) * 32;    // this wave: 32 queries

    const __bf16* qp = q_ws + (size_t)bh * NPOS * 16;
    const __bf16* kp = k_ws + (size_t)bh * NPOS * 16;
    const __bf16* vp = v_ws + (size_t)bh * 16 * NPOS;

    // Q B-frag (32x32x16): lane holds Q[nq0+l5][hi*8 .. hi*8+7]
    bf16x8 qB = load8(qp + (size_t)(nq0 + l5) * 16 + hi * 8);

    bf16x8 ones;
#pragma unroll
    for (int i = 0; i < 8; ++i) ones[i] = (__bf16)1.0f;

    f32x4 o1 = fzero4(), o2 = fzero4(), s1 = fzero4(), s2 = fzero4();

#pragma unroll 2
    for (int nk0 = 0; nk0 < NPOS; nk0 += 32) {
        char* pbuf = p_lds[wave][(nk0 >> 5) & 1];
        // K A-frag (32x32x16): lane holds K[nk0+l5][hi*8 .. hi*8+7]
        bf16x8 kA = load8(kp + (size_t)(nk0 + l5) * 16 + hi * 8);
        f32x16 st;
#pragma unroll
        for (int i = 0; i < 16; ++i) st[i] = 0.0f;
        st = __builtin_amdgcn_mfma_f32_32x32x16_bf16(kA, qB, st, 0, 0, 0);
        // st[reg]: key = nk0 + (reg&3) + 8*(reg>>2) + 4*hi, query = nq0 + l5.
        // exp2 -> bf16 (RN via +0x8000 + perm) -> P[query][key] LDS strip.
#pragma unroll
        for (int g = 0; g < 4; ++g) {
            unsigned u0 = __builtin_bit_cast(unsigned, fexp2(st[4 * g + 0])) + 0x8000u;
            unsigned u1 = __builtin_bit_cast(unsigned, fexp2(st[4 * g + 1])) + 0x8000u;
            unsigned u2 = __builtin_bit_cast(unsigned, fexp2(st[4 * g + 2])) + 0x8000u;
            unsigned u3 = __builtin_bit_cast(unsigned, fexp2(st[4 * g + 3])) + 0x8000u;
            uint2 d;
            d.x = __builtin_amdgcn_perm(u1, u0, 0x07060302u);
            d.y = __builtin_amdgcn_perm(u3, u2, 0x07060302u);
            *reinterpret_cast<uint2*>(pbuf + l5 * PSTR + (8 * g + 4 * hi) * 2) = d;
        }
        // PV (16x16x32): A = V^T, lane: dv = colid, key = quad*8+j (16B);
        // B = P^T from LDS: lane: query = colid (+16), keys quad*8..+7 (16B).
        bf16x8 vA = load8(vp + (size_t)colid * NPOS + nk0 + quad * 8);
        bf16x8 p1 = *reinterpret_cast<bf16x8*>(pbuf + colid * PSTR + quad * 16);
        bf16x8 p2 = *reinterpret_cast<bf16x8*>(pbuf + (colid + 16) * PSTR + quad * 16);
        o1 = __builtin_amdgcn_mfma_f32_16x16x32_bf16(vA, p1, o1, 0, 0, 0);
        s1 = __builtin_amdgcn_mfma_f32_16x16x32_bf16(ones, p1, s1, 0, 0, 0);
        o2 = __builtin_amdgcn_mfma_f32_16x16x32_bf16(vA, p2, o2, 0, 0, 0);
        s2 = __builtin_amdgcn_mfma_f32_16x16x32_bf16(ones, p2, s2, 0, 0, 0);
    }
    // O^T C-layout: row = dv = quad*4+r, col = query = colid; denom = s[any r]
    float inv1 = 1.0f / s1[0];
    float inv2 = 1.0f / s2[0];
    bf16x4 ov1, ov2;
#pragma unroll
    for (int r = 0; r < 4; ++r) {
        ov1[r] = (__bf16)(o1[r] * inv1);
        ov2[r] = (__bf16)(o2[r] * inv2);
    }
    *reinterpret_cast<bf16x4*>(
        attn_ws + ((size_t)b * NPOS + nq0 + colid) * DVC + h * 16 + quad * 4) = ov1;
    *reinterpret_cast<bf16x4*>(
        attn_ws + ((size_t)b * NPOS + nq0 + 16 + colid) * DVC + h * 16 + quad * 4) = ov2;
}

// ---------------------------------------------------------------------------
// Kernel 3: attention output projection (unchanged). grid (16, 2, B).
// ---------------------------------------------------------------------------
__global__ __launch_bounds__(256) void attn_proj(
    const __bf16* __restrict__ attn_ws,  // [B][N][128]
    const __bf16* __restrict__ w_attn,   // [128][128]
    const __bf16* __restrict__ b_attn,   // [128]
    void* __restrict__ out,
    const int* __restrict__ flag)
{
    bool isf32 = (*flag != 0);
    int b    = blockIdx.z;
    int mt   = blockIdx.y;
    int nt   = blockIdx.x;
    int wave = threadIdx.x >> 6;
    int lane = threadIdx.x & 63;
    int quad = lane >> 4, colid = lane & 15;

    int row0 = mt * 64 + wave * 16;
    int n0   = nt * 64;
    const __bf16* ap = attn_ws + ((size_t)b * NPOS + n0) * DVC;

    f32x4 acc[4];
#pragma unroll
    for (int st = 0; st < 4; ++st) acc[st] = fzero4();

#pragma unroll
    for (int k0 = 0; k0 < DVC; k0 += 32) {
        bf16x8 a = load8(w_attn + (size_t)(row0 + colid) * DVC + k0 + quad * 8);
#pragma unroll
        for (int st = 0; st < 4; ++st) {
            bf16x8 bb = load8(ap + (size_t)(st * 16 + colid) * DVC + k0 + quad * 8);
            acc[st] = __builtin_amdgcn_mfma_f32_16x16x32_bf16(a, bb, acc[st], 0, 0, 0);
        }
    }
#pragma unroll
    for (int r = 0; r < 4; ++r) {
        int o = row0 + quad * 4 + r;
        float bias = (float)b_attn[o];
#pragma unroll
        for (int st = 0; st < 4; ++st) {
            int n = n0 + st * 16 + colid;
            float v = acc[st][r] + bias;
            size_t oi = ((size_t)b * OUTC + DVC + o) * NPOS + n;
            if (isf32) ((float*)out)[oi] = v;
            else       ((__bf16*)out)[oi] = (__bf16)v;
        }
    }
}

// ---------------------------------------------------------------------------
// Workspace layout (bytes):
//   0       : flag (int)
//   1.00 MB : wcat [512][256] (256 KB)   1.50 MB : bcat [512]
//   1.75 MB : w_attnc (32 KB)            2.00 MB : b_attnc
//   4 MB    : xT [B][N][256] bf16 (16 MB)
//   20 MB   : attn_ws (8 MB)
//   28 MB   : q_ws (8 MB)   36 MB : k_ws (8 MB)   44 MB : v_ws (8 MB)
// ---------------------------------------------------------------------------
extern "C" void kernel_launch(void* const* d_in, const int* in_sizes, int n_in,
                              void* d_out, int out_size, void* d_ws, size_t ws_size,
                              hipStream_t stream) {
    const void* x      = d_in[0];
    const void* w_qkv  = d_in[1];
    const void* b_qkv  = d_in[2];
    const void* w_attn = d_in[3];
    const void* b_attn = d_in[4];
    const void* w_out  = d_in[5];
    const void* b_out  = d_in[6];

    char* ws = (char*)d_ws;
    int*    flag    = (int*)ws;
    __bf16* wcat    = (__bf16*)(ws + (1u << 20));
    __bf16* bcat    = (__bf16*)(ws + (3u << 19));
    __bf16* w_attnc = (__bf16*)(ws + (7u << 18));
    __bf16* b_attnc = (__bf16*)(ws + (1u << 21));
    __bf16* xT      = (__bf16*)(ws + (1u << 22));
    __bf16* attn_ws = (__bf16*)(ws + (20u << 20));
    __bf16* q_ws    = (__bf16*)(ws + (28u << 20));
    __bf16* k_ws    = (__bf16*)(ws + (36u << 20));
    __bf16* v_ws    = (__bf16*)(ws + (44u << 20));

    detect_dtype<<<1, 256, 0, stream>>>((const unsigned short*)x, flag);
    convert_all<<<(CV_BATT + 255) / 256, 256, 0, stream>>>(
        w_qkv, b_qkv, w_attn, b_attn, w_out, b_out,
        wcat, bcat, w_attnc, b_attnc, flag);
    xpose<<<dim3(NPOS / 64, CIN / 64, BATCH), 256, 0, stream>>>(x, xT, flag);

    qkv_conv_gemm2<<<dim3(NPOS / 64, BATCH, 2), 256, 0, stream>>>(
        xT, wcat, bcat, q_ws, k_ws, v_ws, d_out, flag);
    attention_kernel<<<dim3(NPOS / 128, BATCH * HEADS), 256, 0, stream>>>(
        q_ws, k_ws, v_ws, attn_ws);
    attn_proj<<<dim3(NPOS / 64, 2, BATCH), 256, 0, stream>>>(
        attn_ws, w_attnc, b_attnc, d_out, flag);
}

// Round 2
// 203.540 us; speedup vs baseline: 1.0859x; 1.0403x over previous
//
#include <hip/hip_runtime.h>
#include <hip/hip_bf16.h>

// Problem constants (AttentionConv2d): B=32, CIN=256, H=W=32 -> N=1024,
// DK=DV=128, HEADS=8 -> per-head d=16, OUT=256.
#define BATCH 32
#define CIN   256
#define NPOS  1024
#define DKC   128
#define DVC   128
#define HEADS 8
#define OUTC  256

typedef __bf16 bf16x8 __attribute__((ext_vector_type(8)));
typedef __bf16 bf16x4 __attribute__((ext_vector_type(4)));
typedef float  f32x4  __attribute__((ext_vector_type(4)));
typedef float  f32x16 __attribute__((ext_vector_type(16)));
typedef unsigned u32x4 __attribute__((ext_vector_type(4)));

// q pre-scale: dk^-0.5 * log2(e), so attention can use raw exp2.
#define QSCALE 0.3606737602f

__device__ inline bf16x8 load8(const __bf16* p) {
    return *reinterpret_cast<const bf16x8*>(p);
}
__device__ inline f32x4 fzero4() {
    f32x4 z;
#pragma unroll
    for (int i = 0; i < 4; ++i) z[i] = 0.0f;
    return z;
}
__device__ inline float fexp2(float x) {
#if __has_builtin(__builtin_amdgcn_exp2f)
    return __builtin_amdgcn_exp2f(x);
#else
    return exp2f(x);
#endif
}

// ---------------------------------------------------------------------------
// Kernel D: dtype detector (fp32-as-bf16 halfwords have huge exponents).
// ---------------------------------------------------------------------------
__global__ __launch_bounds__(256) void detect_dtype(const unsigned short* __restrict__ xraw,
                                                    int* __restrict__ flag) {
    __shared__ int s;
    if (threadIdx.x == 0) s = 0;
    __syncthreads();
    int cnt = 0;
#pragma unroll
    for (int j = 0; j < 64; ++j) {
        unsigned short u = xraw[threadIdx.x * 64 + j];
        unsigned int e = (u >> 7) & 0xFF;
        if (e >= 0x92) cnt++;
    }
    if (cnt) atomicAdd(&s, cnt);
    __syncthreads();
    if (threadIdx.x == 0) *flag = (s > 0) ? 1 : 0;
}

// ---------------------------------------------------------------------------
// Kernel C: convert all weight/bias tensors to canonical bf16 in one launch.
// Weights land in ONE contiguous wcat[512][256] (qkv rows 0..383, conv rows
// 384..511) and bcat[512] so the GEMM inner loop has no pointer selects.
// ---------------------------------------------------------------------------
#define CV_WQKV 98304                    // w_qkv 384*256 -> wcat[0..)
#define CV_WOUT (CV_WQKV + 32768)        // w_out 128*256 -> wcat[98304..)
#define CV_BQKV (CV_WOUT + 384)          // b_qkv -> bcat[0..384)
#define CV_BOUT (CV_BQKV + 128)          // b_out -> bcat[384..512)
#define CV_WATT (CV_BOUT + 16384)        // w_attn 128*128
#define CV_BATT (CV_WATT + 128)          // b_attn
__global__ __launch_bounds__(256) void convert_all(
    const void* __restrict__ w_qkv, const void* __restrict__ b_qkv,
    const void* __restrict__ w_attn, const void* __restrict__ b_attn,
    const void* __restrict__ w_out, const void* __restrict__ b_out,
    __bf16* __restrict__ wcat, __bf16* __restrict__ bcat,
    __bf16* __restrict__ w_attnc, __bf16* __restrict__ b_attnc,
    const int* __restrict__ flag) {
    int i = blockIdx.x * 256 + threadIdx.x;
    const void* src; __bf16* dst; int j;
    if      (i < CV_WQKV) { src = w_qkv;  j = i;           dst = wcat + i; }
    else if (i < CV_WOUT) { src = w_out;  j = i - CV_WQKV; dst = wcat + i; }
    else if (i < CV_BQKV) { src = b_qkv;  j = i - CV_WOUT; dst = bcat + j; }
    else if (i < CV_BOUT) { src = b_out;  j = i - CV_BQKV; dst = bcat + 384 + j; }
    else if (i < CV_WATT) { src = w_attn; j = i - CV_BOUT; dst = w_attnc + j; }
    else if (i < CV_BATT) { src = b_attn; j = i - CV_WATT; dst = b_attnc + j; }
    else return;
    if (*flag) *dst = (__bf16)((const float*)src)[j];
    else       *dst = ((const __bf16*)src)[j];
}

// ---------------------------------------------------------------------------
// Kernel X: transpose+convert x [B][C][N] (fp32 or bf16) -> xT [B][N][C] bf16.
// 64x64 tiles; reads fully coalesced (256B/wave), writes 128B-contiguous rows.
// grid (N/64=16, C/64=4, B=32) = 2048 blocks, block 256.
// ---------------------------------------------------------------------------
__global__ __launch_bounds__(256) void xpose(
    const void* __restrict__ xv, __bf16* __restrict__ xT,
    const int* __restrict__ flag) {
    __shared__ __bf16 tile[64][72];  // [n][c], pad to 72 (9216 B)
    bool isf32 = (*flag != 0);
    int b = blockIdx.z, c0 = blockIdx.y * 64, n0 = blockIdx.x * 64;
    int t = threadIdx.x, nl = t & 63, cb = t >> 6;
#pragma unroll
    for (int cs = 0; cs < 16; ++cs) {
        int cw = cs * 4 + cb;
        size_t gi = ((size_t)b * CIN + c0 + cw) * NPOS + n0 + nl;
        float v = isf32 ? ((const float*)xv)[gi] : (float)((const __bf16*)xv)[gi];
        tile[nl][cw] = (__bf16)v;
    }
    __syncthreads();
    int row = t >> 2, seg = t & 3;
    bf16x8 v0 = *reinterpret_cast<const bf16x8*>(&tile[row][seg * 16]);
    bf16x8 v1 = *reinterpret_cast<const bf16x8*>(&tile[row][seg * 16 + 8]);
    __bf16* dst = xT + ((size_t)b * NPOS + n0 + row) * CIN + c0 + seg * 16;
    *reinterpret_cast<bf16x8*>(dst)     = v0;
    *reinterpret_cast<bf16x8*>(dst + 8) = v1;
}

// ---------------------------------------------------------------------------
// Kernel 1 (v2): LDS-free, barrier-free register-streaming QKV+conv GEMM.
// C[o=512][n=B*1024] = wcat[512][256] x xT^T; both operands are direct 16B
// load8 in native mfma_16x16x32 fragment layout (row-major [*][256] bf16).
// Wave tile = 64 rows x 64 cols (acc 4x4 f32x4 = 64 VGPR). Block = 4 waves =
// 256 rows. grid (N/64=16, B=32, rowhalf=2) = 1024 blocks -> 4 blocks/CU,
// 16 waves/CU. Epilogue: q/k as coalesced bf16x4 stores; v/conv scalar.
// ---------------------------------------------------------------------------
__global__ __launch_bounds__(256, 4) void qkv_conv_gemm2(
    const __bf16* __restrict__ xT,    // [B][N][256]
    const __bf16* __restrict__ wcat,  // [512][256]
    const __bf16* __restrict__ bcat,  // [512]
    __bf16* __restrict__ q_ws,        // [B*H][N][16]
    __bf16* __restrict__ k_ws,        // [B*H][N][16]
    __bf16* __restrict__ v_ws,        // [B*H][16][N]
    void* __restrict__ out,           // [B][256][N], dtype per flag
    const int* __restrict__ flag)
{
    int b   = blockIdx.y;
    int n0  = blockIdx.x * 64;
    int z   = blockIdx.z;
    int wave = threadIdx.x >> 6;
    int lane = threadIdx.x & 63;
    int quad = lane >> 4, colid = lane & 15;
    int row0 = z * 256 + wave * 64;

    const __bf16* xp = xT + ((size_t)b * NPOS + n0) * CIN;
    const __bf16* wp = wcat + (size_t)(row0 + colid) * CIN + quad * 8;
    const __bf16* bp = xp + (size_t)colid * CIN + quad * 8;

    f32x4 acc[4][4];
#pragma unroll
    for (int rt = 0; rt < 4; ++rt)
#pragma unroll
        for (int st = 0; st < 4; ++st) acc[rt][st] = fzero4();

#pragma unroll
    for (int k0 = 0; k0 < CIN; k0 += 32) {
        bf16x8 aA[4], bB[4];
#pragma unroll
        for (int rt = 0; rt < 4; ++rt)
            aA[rt] = load8(wp + (size_t)rt * 16 * CIN + k0);
#pragma unroll
        for (int st = 0; st < 4; ++st)
            bB[st] = load8(bp + (size_t)st * 16 * CIN + k0);
#pragma unroll
        for (int rt = 0; rt < 4; ++rt)
#pragma unroll
            for (int st = 0; st < 4; ++st)
                acc[rt][st] = __builtin_amdgcn_mfma_f32_16x16x32_bf16(aA[rt], bB[st], acc[rt][st], 0, 0, 0);
    }

    bool isf32 = (*flag != 0);
#pragma unroll
    for (int rt = 0; rt < 4; ++rt) {
        int obase = row0 + rt * 16;  // uniform per wave; 16 consecutive o
        float bias[4];
#pragma unroll
        for (int r = 0; r < 4; ++r) bias[r] = (float)bcat[obase + quad * 4 + r];

        if (obase < DKC) {                       // ---- q: [B*H][N][16]
            int h = obase >> 4;
            __bf16* qb = q_ws + (((size_t)b * HEADS + h) * NPOS + n0) * 16 + quad * 4;
#pragma unroll
            for (int st = 0; st < 4; ++st) {
                bf16x4 ov;
#pragma unroll
                for (int r = 0; r < 4; ++r)
                    ov[r] = (__bf16)((acc[rt][st][r] + bias[r]) * QSCALE);
                *reinterpret_cast<bf16x4*>(qb + (size_t)(st * 16 + colid) * 16) = ov;
            }
        } else if (obase < 2 * DKC) {            // ---- k: [B*H][N][16]
            int h = (obase - DKC) >> 4;
            __bf16* kb = k_ws + (((size_t)b * HEADS + h) * NPOS + n0) * 16 + quad * 4;
#pragma unroll
            for (int st = 0; st < 4; ++st) {
                bf16x4 ov;
#pragma unroll
                for (int r = 0; r < 4; ++r)
                    ov[r] = (__bf16)(acc[rt][st][r] + bias[r]);
                *reinterpret_cast<bf16x4*>(kb + (size_t)(st * 16 + colid) * 16) = ov;
            }
        } else if (obase < 384) {                // ---- v: [B*H][16][N]
            int h = (obase - 2 * DKC) >> 4;
            __bf16* vb = v_ws + (((size_t)b * HEADS + h) * 16 + quad * 4) * NPOS + n0 + colid;
#pragma unroll
            for (int r = 0; r < 4; ++r)
#pragma unroll
                for (int st = 0; st < 4; ++st)
                    vb[(size_t)r * NPOS + st * 16] = (__bf16)(acc[rt][st][r] + bias[r]);
        } else {                                  // ---- conv out: [B][0..128][N]
            int oc = obase - 384 + quad * 4;
#pragma unroll
            for (int r = 0; r < 4; ++r) {
                size_t ob = ((size_t)b * OUTC + oc + r) * NPOS + n0 + colid;
#pragma unroll
                for (int st = 0; st < 4; ++st) {
                    float v = acc[rt][st][r] + bias[r];
                    if (isf32) ((float*)out)[ob + st * 16] = v;
                    else       ((__bf16*)out)[ob + st * 16] = (__bf16)v;
                }
            }
        }
    }
}

// ---------------------------------------------------------------------------
// Kernel 2 (v3): attention with ZERO LDS — P stays in registers (T12).
// Wave owns 32 queries, streams keys in windows of 32.
//  QK^T: one v_mfma_f32_32x32x16_bf16, C = hoisted zero16 (no per-window
//    re-zero). Output S^T: query = lane&31, key = (reg&3)+8*(reg>>2)+4*hi.
//  exp2 -> v_cvt_pk_bf16_f32 pairs -> v_permlane32_swap_b32: lanes x / x+32
//    hold the SAME query with complementary keys (+4*hi), so one swap per
//    word-pair yields the PV B-frag directly (col=query=l5, k=hi*8+j).
//  PV: two v_mfma_f32_32x32x16_bf16 per window (keys 0-15 / 16-31).
//    A rows 0-15 = V[dv][key] (masked load, l5<16), rows 16-31 = 1.0 ->
//    C rows 16+ are the softmax denominator. No separate ones-MFMA.
// grid (N/128=8, B*H=256), block 256 (4 independent waves), no barriers.
// ---------------------------------------------------------------------------
__global__ __launch_bounds__(256, 4) void attention_kernel(
    const __bf16* __restrict__ q_ws,   // [B*H][N][16]
    const __bf16* __restrict__ k_ws,   // [B*H][N][16]
    const __bf16* __restrict__ v_ws,   // [B*H][16][N]
    __bf16* __restrict__ attn_ws)      // [B][N][128]
{
    int bh   = blockIdx.y;
    int b    = bh >> 3, h = bh & 7;
    int wave = threadIdx.x >> 6;
    int lane = threadIdx.x & 63;
    int l5   = lane & 31, hi = lane >> 5;       // 32x32 frag coords
    int nq0  = (blockIdx.x * 4 + wave) * 32;    // this wave: 32 queries

    const __bf16* qp = q_ws + (size_t)bh * NPOS * 16;
    const __bf16* kp = k_ws + (size_t)bh * NPOS * 16;
    const __bf16* vp = v_ws + (size_t)bh * 16 * NPOS;

    // Q B-frag (32x32x16): lane holds Q[nq0+l5][hi*8 .. hi*8+7]
    bf16x8 qB = load8(qp + (size_t)(nq0 + l5) * 16 + hi * 8);

    // PV A-operand: rows 0-15 = V (dv = l5), rows 16-31 = 1.0 (denominator).
    // Lanes l5>=16 keep the ones initialization forever.
    bf16x8 vA0, vA1;
#pragma unroll
    for (int i = 0; i < 8; ++i) { vA0[i] = (__bf16)1.0f; vA1[i] = (__bf16)1.0f; }
    const __bf16* vrow = vp + (size_t)l5 * NPOS + hi * 8;  // valid when l5<16

    f32x16 zero16;
#pragma unroll
    for (int i = 0; i < 16; ++i) zero16[i] = 0.0f;
    f32x16 acc = zero16;

#pragma unroll 2
    for (int nk0 = 0; nk0 < NPOS; nk0 += 32) {
        // K A-frag (32x32x16): lane holds K[nk0+l5][hi*8 .. hi*8+7]
        bf16x8 kA = load8(kp + (size_t)(nk0 + l5) * 16 + hi * 8);
        if (l5 < 16) {
            vA0 = load8(vrow + nk0);        // keys nk0+0..15  (k=hi*8+j)
            vA1 = load8(vrow + nk0 + 16);   // keys nk0+16..31
        }
        f32x16 st = __builtin_amdgcn_mfma_f32_32x32x16_bf16(kA, qB, zero16, 0, 0, 0);
        // st[reg]: key = nk0 + (reg&3) + 8*(reg>>2) + 4*hi, query = nq0 + l5.
        unsigned w[8];
#pragma unroll
        for (int m = 0; m < 4; ++m) {
            float e0 = fexp2(st[4 * m + 0]);
            float e1 = fexp2(st[4 * m + 1]);
            float e2 = fexp2(st[4 * m + 2]);
            float e3 = fexp2(st[4 * m + 3]);
            unsigned lo, hw;
            asm("v_cvt_pk_bf16_f32 %0, %1, %2" : "=v"(lo) : "v"(e0), "v"(e1));
            asm("v_cvt_pk_bf16_f32 %0, %1, %2" : "=v"(hw) : "v"(e2), "v"(e3));
            w[2 * m]     = lo;   // keys (+0,+1) of group m  (+4*hi)
            w[2 * m + 1] = hw;   // keys (+2,+3) of group m  (+4*hi)
        }
        // Swap lane-halves: after these, {w0,w1,w2,w3} is the B-frag for keys
        // nk0+0..15 (per-lane keys hi*8..hi*8+7) and {w4,w5,w6,w7} for
        // keys nk0+16..31.
        asm("v_permlane32_swap_b32 %0, %1" : "+v"(w[0]), "+v"(w[2]));
        asm("v_permlane32_swap_b32 %0, %1" : "+v"(w[1]), "+v"(w[3]));
        asm("v_permlane32_swap_b32 %0, %1" : "+v"(w[4]), "+v"(w[6]));
        asm("v_permlane32_swap_b32 %0, %1" : "+v"(w[5]), "+v"(w[7]));
        u32x4 t1 = {w[0], w[1], w[2], w[3]};
        u32x4 t2 = {w[4], w[5], w[6], w[7]};
        bf16x8 pB1 = __builtin_bit_cast(bf16x8, t1);
        bf16x8 pB2 = __builtin_bit_cast(bf16x8, t2);
        acc = __builtin_amdgcn_mfma_f32_32x32x16_bf16(vA0, pB1, acc, 0, 0, 0);
        acc = __builtin_amdgcn_mfma_f32_32x32x16_bf16(vA1, pB2, acc, 0, 0, 0);
    }
    // acc rows: (reg&3)+8*(reg>>2)+4*hi, col = query = l5.
    // regs 0-7 -> rows 0-15 = O^T[dv][query]; regs 8-15 -> rows 16-31 = denom.
    float inv = 1.0f / acc[8];
    bf16x4 o0, o1;
#pragma unroll
    for (int r = 0; r < 4; ++r) {
        o0[r] = (__bf16)(acc[r] * inv);       // dv = r + 4*hi
        o1[r] = (__bf16)(acc[4 + r] * inv);   // dv = 8 + r + 4*hi
    }
    __bf16* ob = attn_ws + ((size_t)b * NPOS + nq0 + l5) * DVC + h * 16;
    *reinterpret_cast<bf16x4*>(ob + 4 * hi)     = o0;
    *reinterpret_cast<bf16x4*>(ob + 8 + 4 * hi) = o1;
}

// ---------------------------------------------------------------------------
// Kernel 3: attention output projection (unchanged). grid (16, 2, B).
// ---------------------------------------------------------------------------
__global__ __launch_bounds__(256) void attn_proj(
    const __bf16* __restrict__ attn_ws,  // [B][N][128]
    const __bf16* __restrict__ w_attn,   // [128][128]
    const __bf16* __restrict__ b_attn,   // [128]
    void* __restrict__ out,
    const int* __restrict__ flag)
{
    bool isf32 = (*flag != 0);
    int b    = blockIdx.z;
    int mt   = blockIdx.y;
    int nt   = blockIdx.x;
    int wave = threadIdx.x >> 6;
    int lane = threadIdx.x & 63;
    int quad = lane >> 4, colid = lane & 15;

    int row0 = mt * 64 + wave * 16;
    int n0   = nt * 64;
    const __bf16* ap = attn_ws + ((size_t)b * NPOS + n0) * DVC;

    f32x4 acc[4];
#pragma unroll
    for (int st = 0; st < 4; ++st) acc[st] = fzero4();

#pragma unroll
    for (int k0 = 0; k0 < DVC; k0 += 32) {
        bf16x8 a = load8(w_attn + (size_t)(row0 + colid) * DVC + k0 + quad * 8);
#pragma unroll
        for (int st = 0; st < 4; ++st) {
            bf16x8 bb = load8(ap + (size_t)(st * 16 + colid) * DVC + k0 + quad * 8);
            acc[st] = __builtin_amdgcn_mfma_f32_16x16x32_bf16(a, bb, acc[st], 0, 0, 0);
        }
    }
#pragma unroll
    for (int r = 0; r < 4; ++r) {
        int o = row0 + quad * 4 + r;
        float bias = (float)b_attn[o];
#pragma unroll
        for (int st = 0; st < 4; ++st) {
            int n = n0 + st * 16 + colid;
            float v = acc[st][r] + bias;
            size_t oi = ((size_t)b * OUTC + DVC + o) * NPOS + n;
            if (isf32) ((float*)out)[oi] = v;
            else       ((__bf16*)out)[oi] = (__bf16)v;
        }
    }
}

// ---------------------------------------------------------------------------
// Workspace layout (bytes):
//   0       : flag (int)
//   1.00 MB : wcat [512][256] (256 KB)   1.50 MB : bcat [512]
//   1.75 MB : w_attnc (32 KB)            2.00 MB : b_attnc
//   4 MB    : xT [B][N][256] bf16 (16 MB)
//   20 MB   : attn_ws (8 MB)
//   28 MB   : q_ws (8 MB)   36 MB : k_ws (8 MB)   44 MB : v_ws (8 MB)
// ---------------------------------------------------------------------------
extern "C" void kernel_launch(void* const* d_in, const int* in_sizes, int n_in,
                              void* d_out, int out_size, void* d_ws, size_t ws_size,
                              hipStream_t stream) {
    const void* x      = d_in[0];
    const void* w_qkv  = d_in[1];
    const void* b_qkv  = d_in[2];
    const void* w_attn = d_in[3];
    const void* b_attn = d_in[4];
    const void* w_out  = d_in[5];
    const void* b_out  = d_in[6];

    char* ws = (char*)d_ws;
    int*    flag    = (int*)ws;
    __bf16* wcat    = (__bf16*)(ws + (1u << 20));
    __bf16* bcat    = (__bf16*)(ws + (3u << 19));
    __bf16* w_attnc = (__bf16*)(ws + (7u << 18));
    __bf16* b_attnc = (__bf16*)(ws + (1u << 21));
    __bf16* xT      = (__bf16*)(ws + (1u << 22));
    __bf16* attn_ws = (__bf16*)(ws + (20u << 20));
    __bf16* q_ws    = (__bf16*)(ws + (28u << 20));
    __bf16* k_ws    = (__bf16*)(ws + (36u << 20));
    __bf16* v_ws    = (__bf16*)(ws + (44u << 20));

    detect_dtype<<<1, 256, 0, stream>>>((const unsigned short*)x, flag);
    convert_all<<<(CV_BATT + 255) / 256, 256, 0, stream>>>(
        w_qkv, b_qkv, w_attn, b_attn, w_out, b_out,
        wcat, bcat, w_attnc, b_attnc, flag);
    xpose<<<dim3(NPOS / 64, CIN / 64, BATCH), 256, 0, stream>>>(x, xT, flag);

    qkv_conv_gemm2<<<dim3(NPOS / 64, BATCH, 2), 256, 0, stream>>>(
        xT, wcat, bcat, q_ws, k_ws, v_ws, d_out, flag);
    attention_kernel<<<dim3(NPOS / 128, BATCH * HEADS), 256, 0, stream>>>(
        q_ws, k_ws, v_ws, attn_ws);
    attn_proj<<<dim3(NPOS / 64, 2, BATCH), 256, 0, stream>>>(
        attn_ws, w_attnc, b_attnc, d_out, flag);
}

// Round 3
// 188.122 us; speedup vs baseline: 1.1749x; 1.0820x over previous
//
#include <hip/hip_runtime.h>
#include <hip/hip_bf16.h>

// Problem constants (AttentionConv2d): B=32, CIN=256, H=W=32 -> N=1024,
// DK=DV=128, HEADS=8 -> per-head d=16, OUT=256.
#define BATCH 32
#define CIN   256
#define NPOS  1024
#define DKC   128
#define DVC   128
#define HEADS 8
#define OUTC  256

typedef __bf16 bf16x8 __attribute__((ext_vector_type(8)));
typedef __bf16 bf16x4 __attribute__((ext_vector_type(4)));
typedef float  f32x4  __attribute__((ext_vector_type(4)));
typedef float  f32x16 __attribute__((ext_vector_type(16)));
typedef unsigned u32x4 __attribute__((ext_vector_type(4)));

// q pre-scale: dk^-0.5 * log2(e), so attention can use raw exp2.
#define QSCALE 0.3606737602f

__device__ inline bf16x8 load8(const __bf16* p) {
    return *reinterpret_cast<const bf16x8*>(p);
}
__device__ inline f32x4 fzero4() {
    f32x4 z;
#pragma unroll
    for (int i = 0; i < 4; ++i) z[i] = 0.0f;
    return z;
}
__device__ inline float fexp2(float x) {
#if __has_builtin(__builtin_amdgcn_exp2f)
    return __builtin_amdgcn_exp2f(x);
#else
    return exp2f(x);
#endif
}

// ---------------------------------------------------------------------------
// Kernel D: dtype detector (fp32-as-bf16 halfwords have huge exponents).
// ---------------------------------------------------------------------------
__global__ __launch_bounds__(256) void detect_dtype(const unsigned short* __restrict__ xraw,
                                                    int* __restrict__ flag) {
    __shared__ int s;
    if (threadIdx.x == 0) s = 0;
    __syncthreads();
    int cnt = 0;
#pragma unroll
    for (int j = 0; j < 64; ++j) {
        unsigned short u = xraw[threadIdx.x * 64 + j];
        unsigned int e = (u >> 7) & 0xFF;
        if (e >= 0x92) cnt++;
    }
    if (cnt) atomicAdd(&s, cnt);
    __syncthreads();
    if (threadIdx.x == 0) *flag = (s > 0) ? 1 : 0;
}

// ---------------------------------------------------------------------------
// Kernel C: convert all weight/bias tensors to canonical bf16 in one launch.
// Weights land in ONE contiguous wcat[512][256] (qkv rows 0..383, conv rows
// 384..511) and bcat[512] so the GEMM inner loop has no pointer selects.
// ---------------------------------------------------------------------------
#define CV_WQKV 98304                    // w_qkv 384*256 -> wcat[0..)
#define CV_WOUT (CV_WQKV + 32768)        // w_out 128*256 -> wcat[98304..)
#define CV_BQKV (CV_WOUT + 384)          // b_qkv -> bcat[0..384)
#define CV_BOUT (CV_BQKV + 128)          // b_out -> bcat[384..512)
#define CV_WATT (CV_BOUT + 16384)        // w_attn 128*128
#define CV_BATT (CV_WATT + 128)          // b_attn
__global__ __launch_bounds__(256) void convert_all(
    const void* __restrict__ w_qkv, const void* __restrict__ b_qkv,
    const void* __restrict__ w_attn, const void* __restrict__ b_attn,
    const void* __restrict__ w_out, const void* __restrict__ b_out,
    __bf16* __restrict__ wcat, __bf16* __restrict__ bcat,
    __bf16* __restrict__ w_attnc, __bf16* __restrict__ b_attnc,
    const int* __restrict__ flag) {
    int i = blockIdx.x * 256 + threadIdx.x;
    const void* src; __bf16* dst; int j;
    if      (i < CV_WQKV) { src = w_qkv;  j = i;           dst = wcat + i; }
    else if (i < CV_WOUT) { src = w_out;  j = i - CV_WQKV; dst = wcat + i; }
    else if (i < CV_BQKV) { src = b_qkv;  j = i - CV_WOUT; dst = bcat + j; }
    else if (i < CV_BOUT) { src = b_out;  j = i - CV_BQKV; dst = bcat + 384 + j; }
    else if (i < CV_WATT) { src = w_attn; j = i - CV_BOUT; dst = w_attnc + j; }
    else if (i < CV_BATT) { src = b_attn; j = i - CV_WATT; dst = b_attnc + j; }
    else return;
    if (*flag) *dst = (__bf16)((const float*)src)[j];
    else       *dst = ((const __bf16*)src)[j];
}

// ---------------------------------------------------------------------------
// Kernel X: transpose+convert x [B][C][N] (fp32 or bf16) -> xT [B][N][C] bf16.
// 64x64 tiles; reads fully coalesced (256B/wave), writes 128B-contiguous rows.
// grid (N/64=16, C/64=4, B=32) = 2048 blocks, block 256.
// ---------------------------------------------------------------------------
__global__ __launch_bounds__(256) void xpose(
    const void* __restrict__ xv, __bf16* __restrict__ xT,
    const int* __restrict__ flag) {
    __shared__ __bf16 tile[64][72];  // [n][c], pad to 72 (9216 B)
    bool isf32 = (*flag != 0);
    int b = blockIdx.z, c0 = blockIdx.y * 64, n0 = blockIdx.x * 64;
    int t = threadIdx.x, nl = t & 63, cb = t >> 6;
#pragma unroll
    for (int cs = 0; cs < 16; ++cs) {
        int cw = cs * 4 + cb;
        size_t gi = ((size_t)b * CIN + c0 + cw) * NPOS + n0 + nl;
        float v = isf32 ? ((const float*)xv)[gi] : (float)((const __bf16*)xv)[gi];
        tile[nl][cw] = (__bf16)v;
    }
    __syncthreads();
    int row = t >> 2, seg = t & 3;
    bf16x8 v0 = *reinterpret_cast<const bf16x8*>(&tile[row][seg * 16]);
    bf16x8 v1 = *reinterpret_cast<const bf16x8*>(&tile[row][seg * 16 + 8]);
    __bf16* dst = xT + ((size_t)b * NPOS + n0 + row) * CIN + c0 + seg * 16;
    *reinterpret_cast<bf16x8*>(dst)     = v0;
    *reinterpret_cast<bf16x8*>(dst + 8) = v1;
}

// ---------------------------------------------------------------------------
// Kernel 1 (v2): LDS-free, barrier-free register-streaming QKV+conv GEMM.
// C[o=512][n=B*1024] = wcat[512][256] x xT^T; both operands are direct 16B
// load8 in native mfma_16x16x32 fragment layout (row-major [*][256] bf16).
// Wave tile = 64 rows x 64 cols (acc 4x4 f32x4 = 64 VGPR). Block = 4 waves =
// 256 rows. grid (N/64=16, B=32, rowhalf=2) = 1024 blocks -> 4 blocks/CU,
// 16 waves/CU. Epilogue: q/k as coalesced bf16x4 stores; v/conv scalar.
// ---------------------------------------------------------------------------
__global__ __launch_bounds__(256, 4) void qkv_conv_gemm2(
    const __bf16* __restrict__ xT,    // [B][N][256]
    const __bf16* __restrict__ wcat,  // [512][256]
    const __bf16* __restrict__ bcat,  // [512]
    __bf16* __restrict__ q_ws,        // [B*H][N][16]
    __bf16* __restrict__ k_ws,        // [B*H][N][16]
    __bf16* __restrict__ v_ws,        // [B*H][16][N]
    void* __restrict__ out,           // [B][256][N], dtype per flag
    const int* __restrict__ flag)
{
    int b   = blockIdx.y;
    int n0  = blockIdx.x * 64;
    int z   = blockIdx.z;
    int wave = threadIdx.x >> 6;
    int lane = threadIdx.x & 63;
    int quad = lane >> 4, colid = lane & 15;
    int row0 = z * 256 + wave * 64;

    const __bf16* xp = xT + ((size_t)b * NPOS + n0) * CIN;
    const __bf16* wp = wcat + (size_t)(row0 + colid) * CIN + quad * 8;
    const __bf16* bp = xp + (size_t)colid * CIN + quad * 8;

    f32x4 acc[4][4];
#pragma unroll
    for (int rt = 0; rt < 4; ++rt)
#pragma unroll
        for (int st = 0; st < 4; ++st) acc[rt][st] = fzero4();

#pragma unroll
    for (int k0 = 0; k0 < CIN; k0 += 32) {
        bf16x8 aA[4], bB[4];
#pragma unroll
        for (int rt = 0; rt < 4; ++rt)
            aA[rt] = load8(wp + (size_t)rt * 16 * CIN + k0);
#pragma unroll
        for (int st = 0; st < 4; ++st)
            bB[st] = load8(bp + (size_t)st * 16 * CIN + k0);
#pragma unroll
        for (int rt = 0; rt < 4; ++rt)
#pragma unroll
            for (int st = 0; st < 4; ++st)
                acc[rt][st] = __builtin_amdgcn_mfma_f32_16x16x32_bf16(aA[rt], bB[st], acc[rt][st], 0, 0, 0);
    }

    bool isf32 = (*flag != 0);
#pragma unroll
    for (int rt = 0; rt < 4; ++rt) {
        int obase = row0 + rt * 16;  // uniform per wave; 16 consecutive o
        float bias[4];
#pragma unroll
        for (int r = 0; r < 4; ++r) bias[r] = (float)bcat[obase + quad * 4 + r];

        if (obase < DKC) {                       // ---- q: [B*H][N][16]
            int h = obase >> 4;
            __bf16* qb = q_ws + (((size_t)b * HEADS + h) * NPOS + n0) * 16 + quad * 4;
#pragma unroll
            for (int st = 0; st < 4; ++st) {
                bf16x4 ov;
#pragma unroll
                for (int r = 0; r < 4; ++r)
                    ov[r] = (__bf16)((acc[rt][st][r] + bias[r]) * QSCALE);
                *reinterpret_cast<bf16x4*>(qb + (size_t)(st * 16 + colid) * 16) = ov;
            }
        } else if (obase < 2 * DKC) {            // ---- k: [B*H][N][16]
            int h = (obase - DKC) >> 4;
            __bf16* kb = k_ws + (((size_t)b * HEADS + h) * NPOS + n0) * 16 + quad * 4;
#pragma unroll
            for (int st = 0; st < 4; ++st) {
                bf16x4 ov;
#pragma unroll
                for (int r = 0; r < 4; ++r)
                    ov[r] = (__bf16)(acc[rt][st][r] + bias[r]);
                *reinterpret_cast<bf16x4*>(kb + (size_t)(st * 16 + colid) * 16) = ov;
            }
        } else if (obase < 384) {                // ---- v: [B*H][16][N]
            int h = (obase - 2 * DKC) >> 4;
            __bf16* vb = v_ws + (((size_t)b * HEADS + h) * 16 + quad * 4) * NPOS + n0 + colid;
#pragma unroll
            for (int r = 0; r < 4; ++r)
#pragma unroll
                for (int st = 0; st < 4; ++st)
                    vb[(size_t)r * NPOS + st * 16] = (__bf16)(acc[rt][st][r] + bias[r]);
        } else {                                  // ---- conv out: [B][0..128][N]
            int oc = obase - 384 + quad * 4;
#pragma unroll
            for (int r = 0; r < 4; ++r) {
                size_t ob = ((size_t)b * OUTC + oc + r) * NPOS + n0 + colid;
#pragma unroll
                for (int st = 0; st < 4; ++st) {
                    float v = acc[rt][st][r] + bias[r];
                    if (isf32) ((float*)out)[ob + st * 16] = v;
                    else       ((__bf16*)out)[ob + st * 16] = (__bf16)v;
                }
            }
        }
    }
}

// ---------------------------------------------------------------------------
// Kernel 2 (v4): zero-LDS register attention, 64 queries/wave, XCD-affine.
// grid (bh=256, N/256=4), block 256 (4 waves x 64 queries). gridDim.x=256 is
// a multiple of 8, so XCD(id) = id%8 = bh%8: ALL blocks sharing one head's
// K/V panel (64 KB) land on the SAME XCD -> per-XCD L2 working set
// 32 heads x 64 KB = 2 MB < 4 MB L2. K/V loads hit L2 after first touch.
// Each wave processes TWO 32-query halves against the same kA/vA registers:
// halves the global-load count per unit of exp/MFMA work.
//  QK^T: v_mfma_f32_32x32x16_bf16, C = hoisted zero16.
//    S^T: query = lane&31, key = (reg&3)+8*(reg>>2)+4*hi.
//  exp2 -> v_cvt_pk_bf16_f32 -> v_permlane32_swap_b32 (lanes x/x+32 hold the
//    same query, complementary keys) -> PV B-frag directly, zero LDS.
//  PV: A rows 0-15 = V[dv][key], rows 16-31 = 1.0 -> C rows 16+ hold the
//    softmax denominator for free.
// ---------------------------------------------------------------------------
__global__ __launch_bounds__(256, 4) void attention_kernel(
    const __bf16* __restrict__ q_ws,   // [B*H][N][16]
    const __bf16* __restrict__ k_ws,   // [B*H][N][16]
    const __bf16* __restrict__ v_ws,   // [B*H][16][N]
    __bf16* __restrict__ attn_ws)      // [B][N][128]
{
    int bh   = blockIdx.x;
    int b    = bh >> 3, h = bh & 7;
    int wave = threadIdx.x >> 6;
    int lane = threadIdx.x & 63;
    int l5   = lane & 31, hi = lane >> 5;          // 32x32 frag coords
    int nq0  = (blockIdx.y * 4 + wave) * 64;       // this wave: 64 queries

    const __bf16* qp = q_ws + (size_t)bh * NPOS * 16;
    const __bf16* kp = k_ws + (size_t)bh * NPOS * 16;
    const __bf16* vp = v_ws + (size_t)bh * 16 * NPOS;

    // Two Q B-frags (32x32x16): lane holds Q[nq][hi*8 .. hi*8+7]
    bf16x8 qB0 = load8(qp + (size_t)(nq0 + l5) * 16 + hi * 8);
    bf16x8 qB1 = load8(qp + (size_t)(nq0 + 32 + l5) * 16 + hi * 8);

    // PV A-operand: rows 0-15 = V (dv = l5), rows 16-31 = 1.0 (denominator).
    bf16x8 vA0, vA1;
#pragma unroll
    for (int i = 0; i < 8; ++i) { vA0[i] = (__bf16)1.0f; vA1[i] = (__bf16)1.0f; }
    const __bf16* vrow = vp + (size_t)l5 * NPOS + hi * 8;  // valid when l5<16

    f32x16 zero16;
#pragma unroll
    for (int i = 0; i < 16; ++i) zero16[i] = 0.0f;
    f32x16 acc0 = zero16, acc1 = zero16;

#pragma unroll 2
    for (int nk0 = 0; nk0 < NPOS; nk0 += 32) {
        // K A-frag (32x32x16): lane holds K[nk0+l5][hi*8 .. hi*8+7]
        bf16x8 kA = load8(kp + (size_t)(nk0 + l5) * 16 + hi * 8);
        if (l5 < 16) {
            vA0 = load8(vrow + nk0);        // keys nk0+0..15  (k=hi*8+j)
            vA1 = load8(vrow + nk0 + 16);   // keys nk0+16..31
        }
#pragma unroll
        for (int half = 0; half < 2; ++half) {
            f32x16 st = __builtin_amdgcn_mfma_f32_32x32x16_bf16(
                kA, half ? qB1 : qB0, zero16, 0, 0, 0);
            // st[reg]: key = nk0+(reg&3)+8*(reg>>2)+4*hi, query = nq0+32*half+l5
            unsigned w[8];
#pragma unroll
            for (int m = 0; m < 4; ++m) {
                float e0 = fexp2(st[4 * m + 0]);
                float e1 = fexp2(st[4 * m + 1]);
                float e2 = fexp2(st[4 * m + 2]);
                float e3 = fexp2(st[4 * m + 3]);
                unsigned lo, hw;
                asm("v_cvt_pk_bf16_f32 %0, %1, %2" : "=v"(lo) : "v"(e0), "v"(e1));
                asm("v_cvt_pk_bf16_f32 %0, %1, %2" : "=v"(hw) : "v"(e2), "v"(e3));
                w[2 * m]     = lo;
                w[2 * m + 1] = hw;
            }
            // Swap lane-halves: {w0..w3} = B-frag keys nk0+0..15,
            // {w4..w7} = keys nk0+16..31 (per-lane keys hi*8..hi*8+7).
            asm("v_permlane32_swap_b32 %0, %1" : "+v"(w[0]), "+v"(w[2]));
            asm("v_permlane32_swap_b32 %0, %1" : "+v"(w[1]), "+v"(w[3]));
            asm("v_permlane32_swap_b32 %0, %1" : "+v"(w[4]), "+v"(w[6]));
            asm("v_permlane32_swap_b32 %0, %1" : "+v"(w[5]), "+v"(w[7]));
            u32x4 t1 = {w[0], w[1], w[2], w[3]};
            u32x4 t2 = {w[4], w[5], w[6], w[7]};
            bf16x8 pB1 = __builtin_bit_cast(bf16x8, t1);
            bf16x8 pB2 = __builtin_bit_cast(bf16x8, t2);
            if (half) {
                acc1 = __builtin_amdgcn_mfma_f32_32x32x16_bf16(vA0, pB1, acc1, 0, 0, 0);
                acc1 = __builtin_amdgcn_mfma_f32_32x32x16_bf16(vA1, pB2, acc1, 0, 0, 0);
            } else {
                acc0 = __builtin_amdgcn_mfma_f32_32x32x16_bf16(vA0, pB1, acc0, 0, 0, 0);
                acc0 = __builtin_amdgcn_mfma_f32_32x32x16_bf16(vA1, pB2, acc0, 0, 0, 0);
            }
        }
    }
    // acc rows: (reg&3)+8*(reg>>2)+4*hi, col = query = l5.
    // regs 0-7 -> rows 0-15 = O^T[dv][query]; regs 8-15 -> rows 16-31 = denom.
#pragma unroll
    for (int half = 0; half < 2; ++half) {
        const f32x16& acc = half ? acc1 : acc0;
        float inv = 1.0f / acc[8];
        bf16x4 o0, o1;
#pragma unroll
        for (int r = 0; r < 4; ++r) {
            o0[r] = (__bf16)(acc[r] * inv);       // dv = r + 4*hi
            o1[r] = (__bf16)(acc[4 + r] * inv);   // dv = 8 + r + 4*hi
        }
        __bf16* ob = attn_ws + ((size_t)b * NPOS + nq0 + 32 * half + l5) * DVC + h * 16;
        *reinterpret_cast<bf16x4*>(ob + 4 * hi)     = o0;
        *reinterpret_cast<bf16x4*>(ob + 8 + 4 * hi) = o1;
    }
}

// ---------------------------------------------------------------------------
// Kernel 3: attention output projection (unchanged). grid (16, 2, B).
// ---------------------------------------------------------------------------
__global__ __launch_bounds__(256) void attn_proj(
    const __bf16* __restrict__ attn_ws,  // [B][N][128]
    const __bf16* __restrict__ w_attn,   // [128][128]
    const __bf16* __restrict__ b_attn,   // [128]
    void* __restrict__ out,
    const int* __restrict__ flag)
{
    bool isf32 = (*flag != 0);
    int b    = blockIdx.z;
    int mt   = blockIdx.y;
    int nt   = blockIdx.x;
    int wave = threadIdx.x >> 6;
    int lane = threadIdx.x & 63;
    int quad = lane >> 4, colid = lane & 15;

    int row0 = mt * 64 + wave * 16;
    int n0   = nt * 64;
    const __bf16* ap = attn_ws + ((size_t)b * NPOS + n0) * DVC;

    f32x4 acc[4];
#pragma unroll
    for (int st = 0; st < 4; ++st) acc[st] = fzero4();

#pragma unroll
    for (int k0 = 0; k0 < DVC; k0 += 32) {
        bf16x8 a = load8(w_attn + (size_t)(row0 + colid) * DVC + k0 + quad * 8);
#pragma unroll
        for (int st = 0; st < 4; ++st) {
            bf16x8 bb = load8(ap + (size_t)(st * 16 + colid) * DVC + k0 + quad * 8);
            acc[st] = __builtin_amdgcn_mfma_f32_16x16x32_bf16(a, bb, acc[st], 0, 0, 0);
        }
    }
#pragma unroll
    for (int r = 0; r < 4; ++r) {
        int o = row0 + quad * 4 + r;
        float bias = (float)b_attn[o];
#pragma unroll
        for (int st = 0; st < 4; ++st) {
            int n = n0 + st * 16 + colid;
            float v = acc[st][r] + bias;
            size_t oi = ((size_t)b * OUTC + DVC + o) * NPOS + n;
            if (isf32) ((float*)out)[oi] = v;
            else       ((__bf16*)out)[oi] = (__bf16)v;
        }
    }
}

// ---------------------------------------------------------------------------
// Workspace layout (bytes):
//   0       : flag (int)
//   1.00 MB : wcat [512][256] (256 KB)   1.50 MB : bcat [512]
//   1.75 MB : w_attnc (32 KB)            2.00 MB : b_attnc
//   4 MB    : xT [B][N][256] bf16 (16 MB)
//   20 MB   : attn_ws (8 MB)
//   28 MB   : q_ws (8 MB)   36 MB : k_ws (8 MB)   44 MB : v_ws (8 MB)
// ---------------------------------------------------------------------------
extern "C" void kernel_launch(void* const* d_in, const int* in_sizes, int n_in,
                              void* d_out, int out_size, void* d_ws, size_t ws_size,
                              hipStream_t stream) {
    const void* x      = d_in[0];
    const void* w_qkv  = d_in[1];
    const void* b_qkv  = d_in[2];
    const void* w_attn = d_in[3];
    const void* b_attn = d_in[4];
    const void* w_out  = d_in[5];
    const void* b_out  = d_in[6];

    char* ws = (char*)d_ws;
    int*    flag    = (int*)ws;
    __bf16* wcat    = (__bf16*)(ws + (1u << 20));
    __bf16* bcat    = (__bf16*)(ws + (3u << 19));
    __bf16* w_attnc = (__bf16*)(ws + (7u << 18));
    __bf16* b_attnc = (__bf16*)(ws + (1u << 21));
    __bf16* xT      = (__bf16*)(ws + (1u << 22));
    __bf16* attn_ws = (__bf16*)(ws + (20u << 20));
    __bf16* q_ws    = (__bf16*)(ws + (28u << 20));
    __bf16* k_ws    = (__bf16*)(ws + (36u << 20));
    __bf16* v_ws    = (__bf16*)(ws + (44u << 20));

    detect_dtype<<<1, 256, 0, stream>>>((const unsigned short*)x, flag);
    convert_all<<<(CV_BATT + 255) / 256, 256, 0, stream>>>(
        w_qkv, b_qkv, w_attn, b_attn, w_out, b_out,
        wcat, bcat, w_attnc, b_attnc, flag);
    xpose<<<dim3(NPOS / 64, CIN / 64, BATCH), 256, 0, stream>>>(x, xT, flag);

    qkv_conv_gemm2<<<dim3(NPOS / 64, BATCH, 2), 256, 0, stream>>>(
        xT, wcat, bcat, q_ws, k_ws, v_ws, d_out, flag);
    attention_kernel<<<dim3(BATCH * HEADS, NPOS / 256), 256, 0, stream>>>(
        q_ws, k_ws, v_ws, attn_ws);
    attn_proj<<<dim3(NPOS / 64, 2, BATCH), 256, 0, stream>>>(
        attn_ws, w_attnc, b_attnc, d_out, flag);
}

// Round 4
// 177.487 us; speedup vs baseline: 1.2453x; 1.0599x over previous
//
#include <hip/hip_runtime.h>
#include <hip/hip_bf16.h>

// Problem constants (AttentionConv2d): B=32, CIN=256, H=W=32 -> N=1024,
// DK=DV=128, HEADS=8 -> per-head d=16, OUT=256.
#define BATCH 32
#define CIN   256
#define NPOS  1024
#define DKC   128
#define DVC   128
#define HEADS 8
#define OUTC  256

typedef __bf16 bf16x8 __attribute__((ext_vector_type(8)));
typedef __bf16 bf16x4 __attribute__((ext_vector_type(4)));
typedef float  f32x4  __attribute__((ext_vector_type(4)));
typedef float  f32x16 __attribute__((ext_vector_type(16)));
typedef unsigned u32x4 __attribute__((ext_vector_type(4)));

// q pre-scale: dk^-0.5 * log2(e), so attention can use raw exp2.
#define QSCALE 0.3606737602f

__device__ inline bf16x8 load8(const __bf16* p) {
    return *reinterpret_cast<const bf16x8*>(p);
}
__device__ inline f32x4 fzero4() {
    f32x4 z;
#pragma unroll
    for (int i = 0; i < 4; ++i) z[i] = 0.0f;
    return z;
}
__device__ inline float fexp2(float x) {
#if __has_builtin(__builtin_amdgcn_exp2f)
    return __builtin_amdgcn_exp2f(x);
#else
    return exp2f(x);
#endif
}

// ---------------------------------------------------------------------------
// Kernel D: dtype detector (fp32-as-bf16 halfwords have huge exponents).
// ---------------------------------------------------------------------------
__global__ __launch_bounds__(256) void detect_dtype(const unsigned short* __restrict__ xraw,
                                                    int* __restrict__ flag) {
    __shared__ int s;
    if (threadIdx.x == 0) s = 0;
    __syncthreads();
    int cnt = 0;
#pragma unroll
    for (int j = 0; j < 64; ++j) {
        unsigned short u = xraw[threadIdx.x * 64 + j];
        unsigned int e = (u >> 7) & 0xFF;
        if (e >= 0x92) cnt++;
    }
    if (cnt) atomicAdd(&s, cnt);
    __syncthreads();
    if (threadIdx.x == 0) *flag = (s > 0) ? 1 : 0;
}

// ---------------------------------------------------------------------------
// Kernel C: convert all weight/bias tensors to canonical bf16 in one launch.
// Weights land in ONE contiguous wcat[512][256] (qkv rows 0..383, conv rows
// 384..511) and bcat[512] so the GEMM inner loop has no pointer selects.
// ---------------------------------------------------------------------------
#define CV_WQKV 98304                    // w_qkv 384*256 -> wcat[0..)
#define CV_WOUT (CV_WQKV + 32768)        // w_out 128*256 -> wcat[98304..)
#define CV_BQKV (CV_WOUT + 384)          // b_qkv -> bcat[0..384)
#define CV_BOUT (CV_BQKV + 128)          // b_out -> bcat[384..512)
#define CV_WATT (CV_BOUT + 16384)        // w_attn 128*128
#define CV_BATT (CV_WATT + 128)          // b_attn
__global__ __launch_bounds__(256) void convert_all(
    const void* __restrict__ w_qkv, const void* __restrict__ b_qkv,
    const void* __restrict__ w_attn, const void* __restrict__ b_attn,
    const void* __restrict__ w_out, const void* __restrict__ b_out,
    __bf16* __restrict__ wcat, __bf16* __restrict__ bcat,
    __bf16* __restrict__ w_attnc, __bf16* __restrict__ b_attnc,
    const int* __restrict__ flag) {
    int i = blockIdx.x * 256 + threadIdx.x;
    const void* src; __bf16* dst; int j;
    if      (i < CV_WQKV) { src = w_qkv;  j = i;           dst = wcat + i; }
    else if (i < CV_WOUT) { src = w_out;  j = i - CV_WQKV; dst = wcat + i; }
    else if (i < CV_BQKV) { src = b_qkv;  j = i - CV_WOUT; dst = bcat + j; }
    else if (i < CV_BOUT) { src = b_out;  j = i - CV_BQKV; dst = bcat + 384 + j; }
    else if (i < CV_WATT) { src = w_attn; j = i - CV_BOUT; dst = w_attnc + j; }
    else if (i < CV_BATT) { src = b_attn; j = i - CV_WATT; dst = b_attnc + j; }
    else return;
    if (*flag) *dst = (__bf16)((const float*)src)[j];
    else       *dst = ((const __bf16*)src)[j];
}

// ---------------------------------------------------------------------------
// Kernel X: transpose+convert x [B][C][N] (fp32 or bf16) -> xT [B][N][C] bf16.
// 64x64 tiles; reads fully coalesced (256B/wave), writes 128B-contiguous rows.
// grid (N/64=16, C/64=4, B=32) = 2048 blocks, block 256.
// ---------------------------------------------------------------------------
__global__ __launch_bounds__(256) void xpose(
    const void* __restrict__ xv, __bf16* __restrict__ xT,
    const int* __restrict__ flag) {
    __shared__ __bf16 tile[64][72];  // [n][c], pad to 72 (9216 B)
    bool isf32 = (*flag != 0);
    int b = blockIdx.z, c0 = blockIdx.y * 64, n0 = blockIdx.x * 64;
    int t = threadIdx.x, nl = t & 63, cb = t >> 6;
#pragma unroll
    for (int cs = 0; cs < 16; ++cs) {
        int cw = cs * 4 + cb;
        size_t gi = ((size_t)b * CIN + c0 + cw) * NPOS + n0 + nl;
        float v = isf32 ? ((const float*)xv)[gi] : (float)((const __bf16*)xv)[gi];
        tile[nl][cw] = (__bf16)v;
    }
    __syncthreads();
    int row = t >> 2, seg = t & 3;
    bf16x8 v0 = *reinterpret_cast<const bf16x8*>(&tile[row][seg * 16]);
    bf16x8 v1 = *reinterpret_cast<const bf16x8*>(&tile[row][seg * 16 + 8]);
    __bf16* dst = xT + ((size_t)b * NPOS + n0 + row) * CIN + c0 + seg * 16;
    *reinterpret_cast<bf16x8*>(dst)     = v0;
    *reinterpret_cast<bf16x8*>(dst + 8) = v1;
}

// ---------------------------------------------------------------------------
// Kernel 1 (v3): LDS-free, barrier-free register-streaming QKV+conv GEMM.
// Same per-wave code as v2, but the two 256-row halves (former blockIdx.z)
// now live in ONE 512-thread block: waves 0-3 -> rows 0..255, waves 4-7 ->
// rows 256..511. All 8 waves stream the SAME xT tile through one CU's L1
// (xT L2 traffic cut ~8x). grid (N/64=16, B=32) = 512 blocks, 2 blocks/CU,
// 16 waves/CU.
// ---------------------------------------------------------------------------
__global__ __launch_bounds__(512, 4) void qkv_conv_gemm2(
    const __bf16* __restrict__ xT,    // [B][N][256]
    const __bf16* __restrict__ wcat,  // [512][256]
    const __bf16* __restrict__ bcat,  // [512]
    __bf16* __restrict__ q_ws,        // [B*H][N][16]
    __bf16* __restrict__ k_ws,        // [B*H][N][16]
    __bf16* __restrict__ v_ws,        // [B*H][16][N]
    void* __restrict__ out,           // [B][256][N], dtype per flag
    const int* __restrict__ flag)
{
    int b   = blockIdx.y;
    int n0  = blockIdx.x * 64;
    int wave = threadIdx.x >> 6;          // 0..7
    int lane = threadIdx.x & 63;
    int quad = lane >> 4, colid = lane & 15;
    int row0 = (wave >> 2) * 256 + (wave & 3) * 64;

    const __bf16* xp = xT + ((size_t)b * NPOS + n0) * CIN;
    const __bf16* wp = wcat + (size_t)(row0 + colid) * CIN + quad * 8;
    const __bf16* bp = xp + (size_t)colid * CIN + quad * 8;

    f32x4 acc[4][4];
#pragma unroll
    for (int rt = 0; rt < 4; ++rt)
#pragma unroll
        for (int st = 0; st < 4; ++st) acc[rt][st] = fzero4();

#pragma unroll
    for (int k0 = 0; k0 < CIN; k0 += 32) {
        bf16x8 aA[4], bB[4];
#pragma unroll
        for (int rt = 0; rt < 4; ++rt)
            aA[rt] = load8(wp + (size_t)rt * 16 * CIN + k0);
#pragma unroll
        for (int st = 0; st < 4; ++st)
            bB[st] = load8(bp + (size_t)st * 16 * CIN + k0);
#pragma unroll
        for (int rt = 0; rt < 4; ++rt)
#pragma unroll
            for (int st = 0; st < 4; ++st)
                acc[rt][st] = __builtin_amdgcn_mfma_f32_16x16x32_bf16(aA[rt], bB[st], acc[rt][st], 0, 0, 0);
    }

    bool isf32 = (*flag != 0);
#pragma unroll
    for (int rt = 0; rt < 4; ++rt) {
        int obase = row0 + rt * 16;  // uniform per wave; 16 consecutive o
        float bias[4];
#pragma unroll
        for (int r = 0; r < 4; ++r) bias[r] = (float)bcat[obase + quad * 4 + r];

        if (obase < DKC) {                       // ---- q: [B*H][N][16]
            int h = obase >> 4;
            __bf16* qb = q_ws + (((size_t)b * HEADS + h) * NPOS + n0) * 16 + quad * 4;
#pragma unroll
            for (int st = 0; st < 4; ++st) {
                bf16x4 ov;
#pragma unroll
                for (int r = 0; r < 4; ++r)
                    ov[r] = (__bf16)((acc[rt][st][r] + bias[r]) * QSCALE);
                *reinterpret_cast<bf16x4*>(qb + (size_t)(st * 16 + colid) * 16) = ov;
            }
        } else if (obase < 2 * DKC) {            // ---- k: [B*H][N][16]
            int h = (obase - DKC) >> 4;
            __bf16* kb = k_ws + (((size_t)b * HEADS + h) * NPOS + n0) * 16 + quad * 4;
#pragma unroll
            for (int st = 0; st < 4; ++st) {
                bf16x4 ov;
#pragma unroll
                for (int r = 0; r < 4; ++r)
                    ov[r] = (__bf16)(acc[rt][st][r] + bias[r]);
                *reinterpret_cast<bf16x4*>(kb + (size_t)(st * 16 + colid) * 16) = ov;
            }
        } else if (obase < 384) {                // ---- v: [B*H][16][N]
            int h = (obase - 2 * DKC) >> 4;
            __bf16* vb = v_ws + (((size_t)b * HEADS + h) * 16 + quad * 4) * NPOS + n0 + colid;
#pragma unroll
            for (int r = 0; r < 4; ++r)
#pragma unroll
                for (int st = 0; st < 4; ++st)
                    vb[(size_t)r * NPOS + st * 16] = (__bf16)(acc[rt][st][r] + bias[r]);
        } else {                                  // ---- conv out: [B][0..128][N]
            int oc = obase - 384 + quad * 4;
#pragma unroll
            for (int r = 0; r < 4; ++r) {
                size_t ob = ((size_t)b * OUTC + oc + r) * NPOS + n0 + colid;
#pragma unroll
                for (int st = 0; st < 4; ++st) {
                    float v = acc[rt][st][r] + bias[r];
                    if (isf32) ((float*)out)[ob + st * 16] = v;
                    else       ((__bf16*)out)[ob + st * 16] = (__bf16)v;
                }
            }
        }
    }
}

// ---------------------------------------------------------------------------
// Kernel 2 (v5): FUSED attention + output projection. Zero LDS in the
// K-loop; one LDS buffer + one barrier to exchange O between heads for the
// 128x128 projection. grid (b=32, N/64=16), block 512: wave = head, each
// wave runs the zero-LDS K-loop for 64 queries of its head.
//   XCD affinity: id = b + 32*nc -> id%8 = b%8; all 16 blocks of a batch on
//   one XCD; per-XCD K/V set = 4 batches x 512 KB = 2 MB < 4 MB L2.
//   QK^T: v_mfma_f32_32x32x16_bf16, C = hoisted zero16.
//   exp2 -> v_cvt_pk_bf16_f32 -> v_permlane32_swap_b32 -> PV B-frag (T12).
//   PV: A rows 0-15 = V[dv][key], rows 16-31 = 1.0 -> denominator free.
//   Epilogue: O/denom -> bf16 -> olds[64 q][128 ch] -> barrier -> each wave
//   computes 16 out-channels x 64 q with 16 MFMA from w_attn, stores fp32.
// ---------------------------------------------------------------------------
#define OSTR 136  // olds row stride in ch (272 B, 16B-aligned)
__global__ __launch_bounds__(512, 4) void attention_kernel(
    const __bf16* __restrict__ q_ws,   // [B*H][N][16]
    const __bf16* __restrict__ k_ws,   // [B*H][N][16]
    const __bf16* __restrict__ v_ws,   // [B*H][16][N]
    const __bf16* __restrict__ w_attn, // [128][128]
    const __bf16* __restrict__ b_attn, // [128]
    void* __restrict__ out,            // [B][256][N], dtype per flag
    const int* __restrict__ flag)
{
    __shared__ __align__(16) __bf16 olds[64][OSTR];  // 17.4 KB
    int b    = blockIdx.x;
    int nq0  = blockIdx.y * 64;
    int wave = threadIdx.x >> 6;                 // = head h
    int lane = threadIdx.x & 63;
    int l5   = lane & 31, hi = lane >> 5;        // 32x32 frag coords
    int h    = wave;
    int bh   = b * HEADS + h;

    const __bf16* qp = q_ws + (size_t)bh * NPOS * 16;
    const __bf16* kp = k_ws + (size_t)bh * NPOS * 16;
    const __bf16* vp = v_ws + (size_t)bh * 16 * NPOS;

    // Two Q B-frags (32x32x16): lane holds Q[nq][hi*8 .. hi*8+7]
    bf16x8 qB0 = load8(qp + (size_t)(nq0 + l5) * 16 + hi * 8);
    bf16x8 qB1 = load8(qp + (size_t)(nq0 + 32 + l5) * 16 + hi * 8);

    // PV A-operand: rows 0-15 = V (dv = l5), rows 16-31 = 1.0 (denominator).
    bf16x8 vA0, vA1;
#pragma unroll
    for (int i = 0; i < 8; ++i) { vA0[i] = (__bf16)1.0f; vA1[i] = (__bf16)1.0f; }
    const __bf16* vrow = vp + (size_t)l5 * NPOS + hi * 8;  // valid when l5<16

    f32x16 zero16;
#pragma unroll
    for (int i = 0; i < 16; ++i) zero16[i] = 0.0f;
    f32x16 acc0 = zero16, acc1 = zero16;

#pragma unroll 2
    for (int nk0 = 0; nk0 < NPOS; nk0 += 32) {
        // K A-frag (32x32x16): lane holds K[nk0+l5][hi*8 .. hi*8+7]
        bf16x8 kA = load8(kp + (size_t)(nk0 + l5) * 16 + hi * 8);
        if (l5 < 16) {
            vA0 = load8(vrow + nk0);        // keys nk0+0..15  (k=hi*8+j)
            vA1 = load8(vrow + nk0 + 16);   // keys nk0+16..31
        }
#pragma unroll
        for (int half = 0; half < 2; ++half) {
            f32x16 st = __builtin_amdgcn_mfma_f32_32x32x16_bf16(
                kA, half ? qB1 : qB0, zero16, 0, 0, 0);
            // st[reg]: key = nk0+(reg&3)+8*(reg>>2)+4*hi, query = nq0+32*half+l5
            unsigned w[8];
#pragma unroll
            for (int m = 0; m < 4; ++m) {
                float e0 = fexp2(st[4 * m + 0]);
                float e1 = fexp2(st[4 * m + 1]);
                float e2 = fexp2(st[4 * m + 2]);
                float e3 = fexp2(st[4 * m + 3]);
                unsigned lo, hw;
                asm("v_cvt_pk_bf16_f32 %0, %1, %2" : "=v"(lo) : "v"(e0), "v"(e1));
                asm("v_cvt_pk_bf16_f32 %0, %1, %2" : "=v"(hw) : "v"(e2), "v"(e3));
                w[2 * m]     = lo;
                w[2 * m + 1] = hw;
            }
            // Swap lane-halves: {w0..w3} = B-frag keys nk0+0..15,
            // {w4..w7} = keys nk0+16..31 (per-lane keys hi*8..hi*8+7).
            asm("v_permlane32_swap_b32 %0, %1" : "+v"(w[0]), "+v"(w[2]));
            asm("v_permlane32_swap_b32 %0, %1" : "+v"(w[1]), "+v"(w[3]));
            asm("v_permlane32_swap_b32 %0, %1" : "+v"(w[4]), "+v"(w[6]));
            asm("v_permlane32_swap_b32 %0, %1" : "+v"(w[5]), "+v"(w[7]));
            u32x4 t1 = {w[0], w[1], w[2], w[3]};
            u32x4 t2 = {w[4], w[5], w[6], w[7]};
            bf16x8 pB1 = __builtin_bit_cast(bf16x8, t1);
            bf16x8 pB2 = __builtin_bit_cast(bf16x8, t2);
            if (half) {
                acc1 = __builtin_amdgcn_mfma_f32_32x32x16_bf16(vA0, pB1, acc1, 0, 0, 0);
                acc1 = __builtin_amdgcn_mfma_f32_32x32x16_bf16(vA1, pB2, acc1, 0, 0, 0);
            } else {
                acc0 = __builtin_amdgcn_mfma_f32_32x32x16_bf16(vA0, pB1, acc0, 0, 0, 0);
                acc0 = __builtin_amdgcn_mfma_f32_32x32x16_bf16(vA1, pB2, acc0, 0, 0, 0);
            }
        }
    }
    // acc rows: (reg&3)+8*(reg>>2)+4*hi, col = query = l5.
    // regs 0-7 -> rows 0-15 = O^T[dv][query]; regs 8-15 -> rows 16-31 = denom.
    // Normalize and deposit this head's 16 dv channels into olds[q][h*16+dv].
#pragma unroll
    for (int half = 0; half < 2; ++half) {
        const f32x16& acc = half ? acc1 : acc0;
        float inv = 1.0f / acc[8];
        bf16x4 o0, o1;
#pragma unroll
        for (int r = 0; r < 4; ++r) {
            o0[r] = (__bf16)(acc[r] * inv);       // dv = r + 4*hi
            o1[r] = (__bf16)(acc[4 + r] * inv);   // dv = 8 + r + 4*hi
        }
        __bf16* ol = &olds[32 * half + l5][h * 16 + 4 * hi];
        *reinterpret_cast<bf16x4*>(ol)     = o0;
        *reinterpret_cast<bf16x4*>(ol + 8) = o1;
    }
    __syncthreads();

    // ---- projection: this wave computes out-channels [h*16, h*16+16) for
    // the block's 64 queries. A = w_attn rows (16B loads, L2-hot), B = olds.
    int quad = lane >> 4, colid = lane & 15;
    int row0 = h * 16;
    f32x4 pacc[4];
#pragma unroll
    for (int st = 0; st < 4; ++st) pacc[st] = fzero4();
#pragma unroll
    for (int k0 = 0; k0 < DVC; k0 += 32) {
        bf16x8 a = load8(w_attn + (size_t)(row0 + colid) * DVC + k0 + quad * 8);
#pragma unroll
        for (int st = 0; st < 4; ++st) {
            bf16x8 bb = *reinterpret_cast<const bf16x8*>(&olds[st * 16 + colid][k0 + quad * 8]);
            pacc[st] = __builtin_amdgcn_mfma_f32_16x16x32_bf16(a, bb, pacc[st], 0, 0, 0);
        }
    }
    bool isf32 = (*flag != 0);
#pragma unroll
    for (int r = 0; r < 4; ++r) {
        int o = row0 + quad * 4 + r;
        float bias = (float)b_attn[o];
#pragma unroll
        for (int st = 0; st < 4; ++st) {
            int n = nq0 + st * 16 + colid;
            float v = pacc[st][r] + bias;
            size_t oi = ((size_t)b * OUTC + DVC + o) * NPOS + n;
            if (isf32) ((float*)out)[oi] = v;
            else       ((__bf16*)out)[oi] = (__bf16)v;
        }
    }
}

// ---------------------------------------------------------------------------
// Workspace layout (bytes):
//   0       : flag (int)
//   1.00 MB : wcat [512][256] (256 KB)   1.50 MB : bcat [512]
//   1.75 MB : w_attnc (32 KB)            2.00 MB : b_attnc
//   4 MB    : xT [B][N][256] bf16 (16 MB)
//   28 MB   : q_ws (8 MB)   36 MB : k_ws (8 MB)   44 MB : v_ws (8 MB)
// ---------------------------------------------------------------------------
extern "C" void kernel_launch(void* const* d_in, const int* in_sizes, int n_in,
                              void* d_out, int out_size, void* d_ws, size_t ws_size,
                              hipStream_t stream) {
    const void* x      = d_in[0];
    const void* w_qkv  = d_in[1];
    const void* b_qkv  = d_in[2];
    const void* w_attn = d_in[3];
    const void* b_attn = d_in[4];
    const void* w_out  = d_in[5];
    const void* b_out  = d_in[6];

    char* ws = (char*)d_ws;
    int*    flag    = (int*)ws;
    __bf16* wcat    = (__bf16*)(ws + (1u << 20));
    __bf16* bcat    = (__bf16*)(ws + (3u << 19));
    __bf16* w_attnc = (__bf16*)(ws + (7u << 18));
    __bf16* b_attnc = (__bf16*)(ws + (1u << 21));
    __bf16* xT      = (__bf16*)(ws + (1u << 22));
    __bf16* q_ws    = (__bf16*)(ws + (28u << 20));
    __bf16* k_ws    = (__bf16*)(ws + (36u << 20));
    __bf16* v_ws    = (__bf16*)(ws + (44u << 20));

    detect_dtype<<<1, 256, 0, stream>>>((const unsigned short*)x, flag);
    convert_all<<<(CV_BATT + 255) / 256, 256, 0, stream>>>(
        w_qkv, b_qkv, w_attn, b_attn, w_out, b_out,
        wcat, bcat, w_attnc, b_attnc, flag);
    xpose<<<dim3(NPOS / 64, CIN / 64, BATCH), 256, 0, stream>>>(x, xT, flag);

    qkv_conv_gemm2<<<dim3(NPOS / 64, BATCH), 512, 0, stream>>>(
        xT, wcat, bcat, q_ws, k_ws, v_ws, d_out, flag);
    attention_kernel<<<dim3(BATCH, NPOS / 64), 512, 0, stream>>>(
        q_ws, k_ws, v_ws, w_attnc, b_attnc, d_out, flag);
}

// Round 5
// 164.700 us; speedup vs baseline: 1.3420x; 1.0776x over previous
//
#include <hip/hip_runtime.h>
#include <hip/hip_bf16.h>

// Problem constants (AttentionConv2d): B=32, CIN=256, H=W=32 -> N=1024,
// DK=DV=128, HEADS=8 -> per-head d=16, OUT=256.
#define BATCH 32
#define CIN   256
#define NPOS  1024
#define DKC   128
#define DVC   128
#define HEADS 8
#define OUTC  256

typedef __bf16 bf16x8 __attribute__((ext_vector_type(8)));
typedef __bf16 bf16x4 __attribute__((ext_vector_type(4)));
typedef float  f32x4  __attribute__((ext_vector_type(4)));
typedef float  f32x16 __attribute__((ext_vector_type(16)));
typedef unsigned u32x4 __attribute__((ext_vector_type(4)));

// q pre-scale: dk^-0.5 * log2(e), so attention can use raw exp2.
#define QSCALE 0.3606737602f

__device__ inline bf16x8 load8(const __bf16* p) {
    return *reinterpret_cast<const bf16x8*>(p);
}
__device__ inline f32x4 fzero4() {
    f32x4 z;
#pragma unroll
    for (int i = 0; i < 4; ++i) z[i] = 0.0f;
    return z;
}
__device__ inline float fexp2(float x) {
#if __has_builtin(__builtin_amdgcn_exp2f)
    return __builtin_amdgcn_exp2f(x);
#else
    return exp2f(x);
#endif
}

// ---------------------------------------------------------------------------
// Kernel D: dtype detector (fp32-as-bf16 halfwords have huge exponents).
// ---------------------------------------------------------------------------
__global__ __launch_bounds__(256) void detect_dtype(const unsigned short* __restrict__ xraw,
                                                    int* __restrict__ flag) {
    __shared__ int s;
    if (threadIdx.x == 0) s = 0;
    __syncthreads();
    int cnt = 0;
#pragma unroll
    for (int j = 0; j < 64; ++j) {
        unsigned short u = xraw[threadIdx.x * 64 + j];
        unsigned int e = (u >> 7) & 0xFF;
        if (e >= 0x92) cnt++;
    }
    if (cnt) atomicAdd(&s, cnt);
    __syncthreads();
    if (threadIdx.x == 0) *flag = (s > 0) ? 1 : 0;
}

// ---------------------------------------------------------------------------
// Kernel C: convert all weight/bias tensors to canonical bf16 in one launch.
// Weights land in ONE contiguous wcat[512][256] (qkv rows 0..383, conv rows
// 384..511) and bcat[512] so the GEMM inner loop has no pointer selects.
// ---------------------------------------------------------------------------
#define CV_WQKV 98304                    // w_qkv 384*256 -> wcat[0..)
#define CV_WOUT (CV_WQKV + 32768)        // w_out 128*256 -> wcat[98304..)
#define CV_BQKV (CV_WOUT + 384)          // b_qkv -> bcat[0..384)
#define CV_BOUT (CV_BQKV + 128)          // b_out -> bcat[384..512)
#define CV_WATT (CV_BOUT + 16384)        // w_attn 128*128
#define CV_BATT (CV_WATT + 128)          // b_attn
__global__ __launch_bounds__(256) void convert_all(
    const void* __restrict__ w_qkv, const void* __restrict__ b_qkv,
    const void* __restrict__ w_attn, const void* __restrict__ b_attn,
    const void* __restrict__ w_out, const void* __restrict__ b_out,
    __bf16* __restrict__ wcat, __bf16* __restrict__ bcat,
    __bf16* __restrict__ w_attnc, __bf16* __restrict__ b_attnc,
    const int* __restrict__ flag) {
    int i = blockIdx.x * 256 + threadIdx.x;
    const void* src; __bf16* dst; int j;
    if      (i < CV_WQKV) { src = w_qkv;  j = i;           dst = wcat + i; }
    else if (i < CV_WOUT) { src = w_out;  j = i - CV_WQKV; dst = wcat + i; }
    else if (i < CV_BQKV) { src = b_qkv;  j = i - CV_WOUT; dst = bcat + j; }
    else if (i < CV_BOUT) { src = b_out;  j = i - CV_BQKV; dst = bcat + 384 + j; }
    else if (i < CV_WATT) { src = w_attn; j = i - CV_BOUT; dst = w_attnc + j; }
    else if (i < CV_BATT) { src = b_attn; j = i - CV_WATT; dst = b_attnc + j; }
    else return;
    if (*flag) *dst = (__bf16)((const float*)src)[j];
    else       *dst = ((const __bf16*)src)[j];
}

// ---------------------------------------------------------------------------
// Kernel 1 (v4): QKV+conv GEMM with FUSED x-transpose (xpose kernel gone).
// Stage x[b][c][n0..n0+64) -> LDS xs[64 n][264 c] bf16 (33.8 KB), coalesced
// global reads (lane = n). Row stride 264 el = 33 x 16B => b128 fragment
// reads are conflict-free. Staging b16 writes are 8-way-conflicted but
// one-shot (~200 cyc/wave). Then the v3 register-streaming MFMA loop:
// A = wcat rows (16B L2-hot loads), B = xs fragments.
// Waves 0-3 -> rows 0..255, waves 4-7 -> rows 256..511 of wcat.
// grid (N/64=16, B=32) = 512 blocks, 512 thr, 2 blocks/CU, 16 waves/CU.
// ---------------------------------------------------------------------------
__global__ __launch_bounds__(512, 4) void qkv_conv_gemm3(
    const void* __restrict__ xv,      // [B][C][N] fp32 or bf16
    const __bf16* __restrict__ wcat,  // [512][256]
    const __bf16* __restrict__ bcat,  // [512]
    __bf16* __restrict__ q_ws,        // [B*H][N][16]
    __bf16* __restrict__ k_ws,        // [B*H][N][16]
    __bf16* __restrict__ v_ws,        // [B*H][16][N]
    void* __restrict__ out,           // [B][256][N], dtype per flag
    const int* __restrict__ flag)
{
    __shared__ __bf16 xs[64][264];    // 33792 B
    bool isf32 = (*flag != 0);
    int b   = blockIdx.y;
    int n0  = blockIdx.x * 64;
    int t   = threadIdx.x;
    int nl  = t & 63, cb = t >> 6;    // cb 0..7

#pragma unroll
    for (int cs = 0; cs < 32; ++cs) {
        int c = cs * 8 + cb;
        size_t gi = ((size_t)b * CIN + c) * NPOS + n0 + nl;
        float v = isf32 ? ((const float*)xv)[gi] : (float)((const __bf16*)xv)[gi];
        xs[nl][c] = (__bf16)v;
    }
    __syncthreads();

    int wave = t >> 6;
    int lane = t & 63;
    int quad = lane >> 4, colid = lane & 15;
    int row0 = (wave >> 2) * 256 + (wave & 3) * 64;

    const __bf16* wp = wcat + (size_t)(row0 + colid) * CIN + quad * 8;

    f32x4 acc[4][4];
#pragma unroll
    for (int rt = 0; rt < 4; ++rt)
#pragma unroll
        for (int st = 0; st < 4; ++st) acc[rt][st] = fzero4();

#pragma unroll
    for (int k0 = 0; k0 < CIN; k0 += 32) {
        bf16x8 aA[4], bB[4];
#pragma unroll
        for (int rt = 0; rt < 4; ++rt)
            aA[rt] = load8(wp + (size_t)rt * 16 * CIN + k0);
#pragma unroll
        for (int st = 0; st < 4; ++st)
            bB[st] = *reinterpret_cast<const bf16x8*>(&xs[st * 16 + colid][k0 + quad * 8]);
#pragma unroll
        for (int rt = 0; rt < 4; ++rt)
#pragma unroll
            for (int st = 0; st < 4; ++st)
                acc[rt][st] = __builtin_amdgcn_mfma_f32_16x16x32_bf16(aA[rt], bB[st], acc[rt][st], 0, 0, 0);
    }

#pragma unroll
    for (int rt = 0; rt < 4; ++rt) {
        int obase = row0 + rt * 16;  // uniform per wave; 16 consecutive o
        float bias[4];
#pragma unroll
        for (int r = 0; r < 4; ++r) bias[r] = (float)bcat[obase + quad * 4 + r];

        if (obase < DKC) {                       // ---- q: [B*H][N][16]
            int h = obase >> 4;
            __bf16* qb = q_ws + (((size_t)b * HEADS + h) * NPOS + n0) * 16 + quad * 4;
#pragma unroll
            for (int st = 0; st < 4; ++st) {
                bf16x4 ov;
#pragma unroll
                for (int r = 0; r < 4; ++r)
                    ov[r] = (__bf16)((acc[rt][st][r] + bias[r]) * QSCALE);
                *reinterpret_cast<bf16x4*>(qb + (size_t)(st * 16 + colid) * 16) = ov;
            }
        } else if (obase < 2 * DKC) {            // ---- k: [B*H][N][16]
            int h = (obase - DKC) >> 4;
            __bf16* kb = k_ws + (((size_t)b * HEADS + h) * NPOS + n0) * 16 + quad * 4;
#pragma unroll
            for (int st = 0; st < 4; ++st) {
                bf16x4 ov;
#pragma unroll
                for (int r = 0; r < 4; ++r)
                    ov[r] = (__bf16)(acc[rt][st][r] + bias[r]);
                *reinterpret_cast<bf16x4*>(kb + (size_t)(st * 16 + colid) * 16) = ov;
            }
        } else if (obase < 384) {                // ---- v: [B*H][16][N]
            int h = (obase - 2 * DKC) >> 4;
            __bf16* vb = v_ws + (((size_t)b * HEADS + h) * 16 + quad * 4) * NPOS + n0 + colid;
#pragma unroll
            for (int r = 0; r < 4; ++r)
#pragma unroll
                for (int st = 0; st < 4; ++st)
                    vb[(size_t)r * NPOS + st * 16] = (__bf16)(acc[rt][st][r] + bias[r]);
        } else {                                  // ---- conv out: [B][0..128][N]
            int oc = obase - 384 + quad * 4;
#pragma unroll
            for (int r = 0; r < 4; ++r) {
                size_t ob = ((size_t)b * OUTC + oc + r) * NPOS + n0 + colid;
#pragma unroll
                for (int st = 0; st < 4; ++st) {
                    float v = acc[rt][st][r] + bias[r];
                    if (isf32) ((float*)out)[ob + st * 16] = v;
                    else       ((__bf16*)out)[ob + st * 16] = (__bf16)v;
                }
            }
        }
    }
}

// ---------------------------------------------------------------------------
// Kernel 2 (v6): fused attention + projection, with one-window K/V register
// PREFETCH. Per window the kA/vA loads for window n+1 are issued BEFORE the
// exp/pack/PV chain of window n (T14 issue-early), hiding ~200-cycle L2
// latency that the compiler was not hoisting (round-4 counters: wall/window
// ~3.3K cy vs ~330 issue -> ~45% unhidden latency). Rotation uses named
// registers (static indexing). Last iteration prefetch wraps to window 0.
// grid (b=32, N/64=16), block 512: wave = head, 64 queries per wave.
//   XCD affinity: id = b + 32*nc -> id%8 = b%8; per-XCD K/V = 2 MB < L2.
//   QK^T: v_mfma_f32_32x32x16_bf16, C = hoisted zero16.
//   exp2 -> v_cvt_pk_bf16_f32 -> v_permlane32_swap_b32 -> PV B-frag (T12).
//   PV: A rows 0-15 = V[dv][key], rows 16-31 = 1.0 -> denominator free.
//   Epilogue: olds[64 q][128 ch] -> barrier -> 16 out-ch x 64 q per wave.
// ---------------------------------------------------------------------------
#define OSTR 136  // olds row stride in ch (272 B, 17x16B -> conflict-free)
__global__ __launch_bounds__(512, 4) void attention_kernel(
    const __bf16* __restrict__ q_ws,   // [B*H][N][16]
    const __bf16* __restrict__ k_ws,   // [B*H][N][16]
    const __bf16* __restrict__ v_ws,   // [B*H][16][N]
    const __bf16* __restrict__ w_attn, // [128][128]
    const __bf16* __restrict__ b_attn, // [128]
    void* __restrict__ out,            // [B][256][N], dtype per flag
    const int* __restrict__ flag)
{
    __shared__ __align__(16) __bf16 olds[64][OSTR];  // 17.4 KB
    int b    = blockIdx.x;
    int nq0  = blockIdx.y * 64;
    int wave = threadIdx.x >> 6;                 // = head h
    int lane = threadIdx.x & 63;
    int l5   = lane & 31, hi = lane >> 5;        // 32x32 frag coords
    int h    = wave;
    int bh   = b * HEADS + h;

    const __bf16* qp = q_ws + (size_t)bh * NPOS * 16;
    const __bf16* kp = k_ws + (size_t)bh * NPOS * 16;
    const __bf16* vp = v_ws + (size_t)bh * 16 * NPOS;

    // Two Q B-frags (32x32x16): lane holds Q[nq][hi*8 .. hi*8+7]
    bf16x8 qB0 = load8(qp + (size_t)(nq0 + l5) * 16 + hi * 8);
    bf16x8 qB1 = load8(qp + (size_t)(nq0 + 32 + l5) * 16 + hi * 8);

    // PV A-operand: rows 0-15 = V (dv = l5), rows 16-31 = 1.0 (denominator).
    bf16x8 vA0, vA1;
#pragma unroll
    for (int i = 0; i < 8; ++i) { vA0[i] = (__bf16)1.0f; vA1[i] = (__bf16)1.0f; }
    const __bf16* vrow = vp + (size_t)l5 * NPOS + hi * 8;  // valid when l5<16

    f32x16 zero16;
#pragma unroll
    for (int i = 0; i < 16; ++i) zero16[i] = 0.0f;
    f32x16 acc0 = zero16, acc1 = zero16;

    // ---- window-0 operand loads (prologue of the prefetch pipeline)
    bf16x8 kA = load8(kp + (size_t)l5 * 16 + hi * 8);
    if (l5 < 16) {
        vA0 = load8(vrow);
        vA1 = load8(vrow + 16);
    }

#pragma unroll 2
    for (int nk0 = 0; nk0 < NPOS; nk0 += 32) {
        // ---- prefetch window n+1 (wraps to 0 on the last iteration)
        int nkn = (nk0 + 32) & (NPOS - 1);
        bf16x8 kA_n = load8(kp + (size_t)(nkn + l5) * 16 + hi * 8);
        bf16x8 vA0_n = vA0, vA1_n = vA1;   // lanes l5>=16 keep the 1.0 rows
        if (l5 < 16) {
            vA0_n = load8(vrow + nkn);
            vA1_n = load8(vrow + nkn + 16);
        }
        // ---- compute window n with the already-resident kA/vA0/vA1
#pragma unroll
        for (int half = 0; half < 2; ++half) {
            f32x16 st = __builtin_amdgcn_mfma_f32_32x32x16_bf16(
                kA, half ? qB1 : qB0, zero16, 0, 0, 0);
            // st[reg]: key = nk0+(reg&3)+8*(reg>>2)+4*hi, query = nq0+32*half+l5
            unsigned w[8];
#pragma unroll
            for (int m = 0; m < 4; ++m) {
                float e0 = fexp2(st[4 * m + 0]);
                float e1 = fexp2(st[4 * m + 1]);
                float e2 = fexp2(st[4 * m + 2]);
                float e3 = fexp2(st[4 * m + 3]);
                unsigned lo, hw;
                asm("v_cvt_pk_bf16_f32 %0, %1, %2" : "=v"(lo) : "v"(e0), "v"(e1));
                asm("v_cvt_pk_bf16_f32 %0, %1, %2" : "=v"(hw) : "v"(e2), "v"(e3));
                w[2 * m]     = lo;
                w[2 * m + 1] = hw;
            }
            // Swap lane-halves: {w0..w3} = B-frag keys nk0+0..15,
            // {w4..w7} = keys nk0+16..31 (per-lane keys hi*8..hi*8+7).
            asm("v_permlane32_swap_b32 %0, %1" : "+v"(w[0]), "+v"(w[2]));
            asm("v_permlane32_swap_b32 %0, %1" : "+v"(w[1]), "+v"(w[3]));
            asm("v_permlane32_swap_b32 %0, %1" : "+v"(w[4]), "+v"(w[6]));
            asm("v_permlane32_swap_b32 %0, %1" : "+v"(w[5]), "+v"(w[7]));
            u32x4 t1 = {w[0], w[1], w[2], w[3]};
            u32x4 t2 = {w[4], w[5], w[6], w[7]};
            bf16x8 pB1 = __builtin_bit_cast(bf16x8, t1);
            bf16x8 pB2 = __builtin_bit_cast(bf16x8, t2);
            if (half) {
                acc1 = __builtin_amdgcn_mfma_f32_32x32x16_bf16(vA0, pB1, acc1, 0, 0, 0);
                acc1 = __builtin_amdgcn_mfma_f32_32x32x16_bf16(vA1, pB2, acc1, 0, 0, 0);
            } else {
                acc0 = __builtin_amdgcn_mfma_f32_32x32x16_bf16(vA0, pB1, acc0, 0, 0, 0);
                acc0 = __builtin_amdgcn_mfma_f32_32x32x16_bf16(vA1, pB2, acc0, 0, 0, 0);
            }
        }
        // ---- rotate
        kA = kA_n; vA0 = vA0_n; vA1 = vA1_n;
    }
    // acc rows: (reg&3)+8*(reg>>2)+4*hi, col = query = l5.
    // regs 0-7 -> rows 0-15 = O^T[dv][query]; regs 8-15 -> rows 16-31 = denom.
    // Normalize and deposit this head's 16 dv channels into olds[q][h*16+dv].
#pragma unroll
    for (int half = 0; half < 2; ++half) {
        const f32x16& acc = half ? acc1 : acc0;
        float inv = 1.0f / acc[8];
        bf16x4 o0, o1;
#pragma unroll
        for (int r = 0; r < 4; ++r) {
            o0[r] = (__bf16)(acc[r] * inv);       // dv = r + 4*hi
            o1[r] = (__bf16)(acc[4 + r] * inv);   // dv = 8 + r + 4*hi
        }
        __bf16* ol = &olds[32 * half + l5][h * 16 + 4 * hi];
        *reinterpret_cast<bf16x4*>(ol)     = o0;
        *reinterpret_cast<bf16x4*>(ol + 8) = o1;
    }
    __syncthreads();

    // ---- projection: this wave computes out-channels [h*16, h*16+16) for
    // the block's 64 queries. A = w_attn rows (16B loads, L2-hot), B = olds.
    int quad = lane >> 4, colid = lane & 15;
    int row0 = h * 16;
    f32x4 pacc[4];
#pragma unroll
    for (int st = 0; st < 4; ++st) pacc[st] = fzero4();
#pragma unroll
    for (int k0 = 0; k0 < DVC; k0 += 32) {
        bf16x8 a = load8(w_attn + (size_t)(row0 + colid) * DVC + k0 + quad * 8);
#pragma unroll
        for (int st = 0; st < 4; ++st) {
            bf16x8 bb = *reinterpret_cast<const bf16x8*>(&olds[st * 16 + colid][k0 + quad * 8]);
            pacc[st] = __builtin_amdgcn_mfma_f32_16x16x32_bf16(a, bb, pacc[st], 0, 0, 0);
        }
    }
    bool isf32 = (*flag != 0);
#pragma unroll
    for (int r = 0; r < 4; ++r) {
        int o = row0 + quad * 4 + r;
        float bias = (float)b_attn[o];
#pragma unroll
        for (int st = 0; st < 4; ++st) {
            int n = nq0 + st * 16 + colid;
            float v = pacc[st][r] + bias;
            size_t oi = ((size_t)b * OUTC + DVC + o) * NPOS + n;
            if (isf32) ((float*)out)[oi] = v;
            else       ((__bf16*)out)[oi] = (__bf16)v;
        }
    }
}

// ---------------------------------------------------------------------------
// Workspace layout (bytes):
//   0       : flag (int)
//   1.00 MB : wcat [512][256] (256 KB)   1.50 MB : bcat [512]
//   1.75 MB : w_attnc (32 KB)            2.00 MB : b_attnc
//   28 MB   : q_ws (8 MB)   36 MB : k_ws (8 MB)   44 MB : v_ws (8 MB)
// ---------------------------------------------------------------------------
extern "C" void kernel_launch(void* const* d_in, const int* in_sizes, int n_in,
                              void* d_out, int out_size, void* d_ws, size_t ws_size,
                              hipStream_t stream) {
    const void* x      = d_in[0];
    const void* w_qkv  = d_in[1];
    const void* b_qkv  = d_in[2];
    const void* w_attn = d_in[3];
    const void* b_attn = d_in[4];
    const void* w_out  = d_in[5];
    const void* b_out  = d_in[6];

    char* ws = (char*)d_ws;
    int*    flag    = (int*)ws;
    __bf16* wcat    = (__bf16*)(ws + (1u << 20));
    __bf16* bcat    = (__bf16*)(ws + (3u << 19));
    __bf16* w_attnc = (__bf16*)(ws + (7u << 18));
    __bf16* b_attnc = (__bf16*)(ws + (1u << 21));
    __bf16* q_ws    = (__bf16*)(ws + (28u << 20));
    __bf16* k_ws    = (__bf16*)(ws + (36u << 20));
    __bf16* v_ws    = (__bf16*)(ws + (44u << 20));

    detect_dtype<<<1, 256, 0, stream>>>((const unsigned short*)x, flag);
    convert_all<<<(CV_BATT + 255) / 256, 256, 0, stream>>>(
        w_qkv, b_qkv, w_attn, b_attn, w_out, b_out,
        wcat, bcat, w_attnc, b_attnc, flag);

    qkv_conv_gemm3<<<dim3(NPOS / 64, BATCH), 512, 0, stream>>>(
        x, wcat, bcat, q_ws, k_ws, v_ws, d_out, flag);
    attention_kernel<<<dim3(BATCH, NPOS / 64), 512, 0, stream>>>(
        q_ws, k_ws, v_ws, w_attnc, b_attnc, d_out, flag);
}